// Round 7
// baseline (434.966 us; speedup 1.0000x reference)
//
#include <hip/hip_runtime.h>
#include <cstdint>
#include <cstddef>

#define BZ 4
#define CD 96
#define LL 9216
#define DD 192
#define NS 16
#define RR 6
#define LC 32
#define NG 288
#define NGRP 16
#define GSZ 18
#define MTOK (BZ * LL)

#define SA 256.0f
#define SW 1024.0f
#define SY 16.0f

typedef _Float16 f16x8 __attribute__((ext_vector_type(8)));
typedef _Float16 f16x4 __attribute__((ext_vector_type(4)));
typedef float f32x4 __attribute__((ext_vector_type(4)));

__device__ __forceinline__ float siluf(float x) {
    return x / (1.f + __expf(-x));
}
__device__ __forceinline__ float softplusf(float x) {
    return fmaxf(x, 0.f) + log1pf(__expf(-fabsf(x)));
}

// ---------------------------------------------------------------------------
__global__ void prep_kernel(const float* kg, const float* kb, const float* kw, const float* kbias,
                            const float* qg, const float* qb, const float* qw, const float* qbias,
                            float* gwK, float* wsumK, float* biasK,
                            float* gwQ, float* wsumQ, float* biasQ) {
    int d = blockIdx.x;
    const float* g  = blockIdx.y ? qg : kg;
    const float* lb = blockIdx.y ? qb : kb;
    const float* w  = blockIdx.y ? qw : kw;
    const float* b2 = blockIdx.y ? qbias : kbias;
    float* gw = blockIdx.y ? gwQ : gwK;
    float* wsv = blockIdx.y ? wsumQ : wsumK;
    float* bv = blockIdx.y ? biasQ : biasK;
    int c = threadIdx.x;
    __shared__ float s1[96], s2[96];
    float wv = w[d * 96 + c];
    float gv = g[c] * wv;
    gw[d * 96 + c] = gv;
    s1[c] = gv;
    s2[c] = lb[c] * wv;
    __syncthreads();
    if (c < 32) { s1[c] += s1[c + 64]; s2[c] += s2[c + 64]; }
    __syncthreads();
    for (int s = 32; s >= 1; s >>= 1) {
        if (c < s) { s1[c] += s1[c + s]; s2[c] += s2[c + s]; }
        __syncthreads();
    }
    if (c == 0) { wsv[d] = s1[0]; bv[d] = b2[d] + s2[0]; }
}

// ---------------------------------------------------------------------------
__global__ __launch_bounds__(256) void split_all_kernel(
    const float* __restrict__ s0, const float* __restrict__ s1, const float* __restrict__ s2,
    const float* __restrict__ s3, const float* __restrict__ s4, const float* __restrict__ s5,
    _Float16* __restrict__ d0h, _Float16* __restrict__ d0l,
    _Float16* __restrict__ d1h, _Float16* __restrict__ d1l,
    _Float16* __restrict__ d2h, _Float16* __restrict__ d2l,
    _Float16* __restrict__ d3h, _Float16* __restrict__ d3l,
    _Float16* __restrict__ d4h, _Float16* __restrict__ d4l,
    _Float16* __restrict__ d5h, _Float16* __restrict__ d5l)
{
    int idx = blockIdx.x * 256 + threadIdx.x;
    const int C0 = 18432, C1 = 18432, C2 = 18432, C3 = 18432, C4 = 73728, C5 = 18432;
    const float* src; _Float16* dh; _Float16* dl; int i; bool pad = false;
    if (idx < C0) { src = s0; dh = d0h; dl = d0l; i = idx; }
    else if (idx < C0 + C1) { src = s1; dh = d1h; dl = d1l; i = idx - C0; }
    else if (idx < C0 + C1 + C2) { src = s2; dh = d2h; dl = d2l; i = idx - C0 - C1; }
    else if (idx < C0 + C1 + C2 + C3) {
        src = s3; dh = d3h; dl = d3l; i = idx - C0 - C1 - C2;
        pad = (i / 384) >= 38;   // dtbc_w: 38 real rows padded to 48
    }
    else if (idx < C0 + C1 + C2 + C3 + C4) { src = s4; dh = d4h; dl = d4l; i = idx - C0 - C1 - C2 - C3; }
    else if (idx < C0 + C1 + C2 + C3 + C4 + C5) { src = s5; dh = d5h; dl = d5l; i = idx - C0 - C1 - C2 - C3 - C4; }
    else return;
    float v = pad ? 0.f : src[i] * SW;
    _Float16 h = (_Float16)v;
    dh[i] = h;
    dl[i] = (_Float16)(v - (float)h);
}

// ---------------------------------------------------------------------------
// Merged MFMA projection (x / K / Q by blockIdx.z), K=96, N=192.
// LN stats are accumulated inside the staging loop (each thread's 24 staged
// elements all belong to token l = tid&63), so no post-barrier LDS re-read.
__global__ __launch_bounds__(256, 4) void mfma_projCH3(
    const float* __restrict__ xA, const float* __restrict__ KA, const float* __restrict__ QA,
    const _Float16* __restrict__ ipWh, const _Float16* __restrict__ ipWl,
    const _Float16* __restrict__ kWh, const _Float16* __restrict__ kWl,
    const _Float16* __restrict__ qWh, const _Float16* __restrict__ qWl,
    const float* __restrict__ wsumK, const float* __restrict__ biasK,
    const float* __restrict__ wsumQ, const float* __restrict__ biasQ,
    float* __restrict__ xin,
    _Float16* __restrict__ KpH, _Float16* __restrict__ KpL,
    _Float16* __restrict__ QpH, _Float16* __restrict__ QpL)
{
    int which = blockIdx.z;
    const float* A = which == 0 ? xA : (which == 1 ? KA : QA);
    const _Float16* Wh = which == 0 ? ipWh : (which == 1 ? kWh : qWh);
    const _Float16* Wl = which == 0 ? ipWl : (which == 1 ? kWl : qWl);
    const float* wsum = which == 1 ? wsumK : wsumQ;
    const float* biasv = which == 1 ? biasK : biasQ;
    _Float16* outH = which == 1 ? KpH : QpH;
    _Float16* outL = which == 1 ? KpL : QpL;
    bool LN = which != 0;

    int b = blockIdx.y;
    int l0 = blockIdx.x * 64;
    int tid = threadIdx.x;
    int lane = tid & 63, w = tid >> 6;

    __shared__ __align__(16) _Float16 Ah[64 * 104];
    __shared__ __align__(16) _Float16 Al[64 * 104];
    __shared__ float sm[64], siv[64];
    __shared__ float red1[256], red2[256];

    {
        float s = 0.f, ss = 0.f;
        #pragma unroll 4
        for (int i = tid; i < 96 * 64; i += 256) {
            int c = i >> 6, l = i & 63;
            float a = A[((size_t)b * CD + c) * LL + l0 + l];
            float v = a * SA;
            _Float16 h = (_Float16)v;
            Ah[l * 104 + c] = h;
            Al[l * 104 + c] = (_Float16)(v - (float)h);
            s += a; ss += a * a;
        }
        if (LN) { red1[tid] = s; red2[tid] = ss; }
    }
    __syncthreads();
    if (LN && tid < 64) {
        float s4 = red1[tid] + red1[tid + 64] + red1[tid + 128] + red1[tid + 192];
        float q4 = red2[tid] + red2[tid + 64] + red2[tid + 128] + red2[tid + 192];
        float m = s4 / 96.f;
        sm[tid] = m;
        siv[tid] = rsqrtf(fmaxf(q4 / 96.f - m * m, 0.f) + 1e-5f);
    }
    if (LN) __syncthreads();

    int col = lane & 15, quad = lane >> 4;
    int n0 = w * 48;
    f32x4 zv4 = {0.f, 0.f, 0.f, 0.f};
    f32x4 acc[4][3];
    #pragma unroll
    for (int mi = 0; mi < 4; mi++)
        #pragma unroll
        for (int ni = 0; ni < 3; ni++) acc[mi][ni] = zv4;
    for (int c0 = 0; c0 < 96; c0 += 32) {
        f16x8 afh[4], afl[4], bfh[3], bfl[3];
        #pragma unroll
        for (int mi = 0; mi < 4; mi++) {
            int off = (16 * mi + col) * 104 + c0 + quad * 8;
            afh[mi] = *(const f16x8*)&Ah[off];
            afl[mi] = *(const f16x8*)&Al[off];
        }
        #pragma unroll
        for (int ni = 0; ni < 3; ni++) {
            size_t off = (size_t)(n0 + ni * 16 + col) * 96 + c0 + quad * 8;
            bfh[ni] = *(const f16x8*)&Wh[off];
            bfl[ni] = *(const f16x8*)&Wl[off];
        }
        #pragma unroll
        for (int mi = 0; mi < 4; mi++)
            #pragma unroll
            for (int ni = 0; ni < 3; ni++) {
                acc[mi][ni] = __builtin_amdgcn_mfma_f32_16x16x32_f16(afh[mi], bfl[ni], acc[mi][ni], 0, 0, 0);
                acc[mi][ni] = __builtin_amdgcn_mfma_f32_16x16x32_f16(afl[mi], bfh[ni], acc[mi][ni], 0, 0, 0);
                acc[mi][ni] = __builtin_amdgcn_mfma_f32_16x16x32_f16(afh[mi], bfh[ni], acc[mi][ni], 0, 0, 0);
            }
    }
    const float isc = 1.f / (SA * SW);
    if (LN) {
        #pragma unroll
        for (int ni = 0; ni < 3; ni++) {
            int d = n0 + ni * 16 + col;
            float wsv = wsum[d];
            float bvv = biasv[d];
            #pragma unroll
            for (int mi = 0; mi < 4; mi++)
                #pragma unroll
                for (int r = 0; r < 4; r++) {
                    int tl = mi * 16 + quad * 4 + r;
                    float v = acc[mi][ni][r] * isc;
                    size_t t = (size_t)b * LL + l0 + tl;
                    v = (v - sm[tl] * wsv) * siv[tl] + bvv;
                    v = siluf(v) * SA;
                    _Float16 h = (_Float16)v;
                    outH[t * DD + d] = h;
                    outL[t * DD + d] = (_Float16)(v - (float)h);
                }
        }
    } else {
        #pragma unroll
        for (int ni = 0; ni < 3; ni++) {
            int d = n0 + ni * 16 + col;
            #pragma unroll
            for (int mi = 0; mi < 4; mi++)
                #pragma unroll
                for (int r = 0; r < 4; r++) {
                    int tl = mi * 16 + quad * 4 + r;
                    size_t t = (size_t)b * LL + l0 + tl;
                    xin[t * DD + d] = acc[mi][ni][r] * isc;
                }
        }
    }
}

// ---------------------------------------------------------------------------
// Depthwise causal conv (k=4) + bias + silu -> split f16 u planes (x SA).
// Register-tiled: 4 tokens x 4 dims per thread, float4 loads, f16x4 stores.
__global__ __launch_bounds__(256) void conv_kernel(const float* __restrict__ xin,
        const float* __restrict__ cw, const float* __restrict__ cb,
        _Float16* __restrict__ uh, _Float16* __restrict__ ul)
{
    int gid = blockIdx.x * 256 + threadIdx.x;
    int dg = gid % (DD / 4);
    int tg = gid / (DD / 4);
    int b = tg / (LL / 4);
    int l0 = (tg % (LL / 4)) * 4;
    size_t rowbase = ((size_t)b * LL + l0) * DD + dg * 4;
    f32x4 r[7];
    #pragma unroll
    for (int j = 0; j < 7; j++) {
        int l = l0 - 3 + j;
        f32x4 z4 = {0.f, 0.f, 0.f, 0.f};
        r[j] = (l >= 0) ? *(const f32x4*)&xin[rowbase + (size_t)(j - 3) * DD] : z4;
    }
    float cwv[4][4], cb4[4];
    #pragma unroll
    for (int e = 0; e < 4; e++) {
        cb4[e] = cb[dg * 4 + e];
        #pragma unroll
        for (int j = 0; j < 4; j++) cwv[e][j] = cw[(dg * 4 + e) * 4 + j];
    }
    #pragma unroll
    for (int tt = 0; tt < 4; tt++) {
        f16x4 oh, ol;
        #pragma unroll
        for (int e = 0; e < 4; e++) {
            float s = cb4[e];
            #pragma unroll
            for (int j = 0; j < 4; j++) s = fmaf(cwv[e][j], r[tt + j][e], s);
            float u = siluf(s) * SA;
            _Float16 h = (_Float16)u;
            oh[e] = h;
            ol[e] = (_Float16)(u - (float)h);
        }
        *(f16x4*)&uh[rowbase + (size_t)tt * DD] = oh;
        *(f16x4*)&ul[rowbase + (size_t)tt * DD] = ol;
    }
}

// ---------------------------------------------------------------------------
// Pipelined 32tok x 48n wave-tile GEMM core (split f16x2, 3-MFMA accumulate).
__device__ __forceinline__ void mfma_set3(
    const f16x8 (&ah)[2], const f16x8 (&al)[2],
    const f16x8 (&bh)[3], const f16x8 (&bl)[3], f32x4 (&acc)[2][3])
{
    #pragma unroll
    for (int mi = 0; mi < 2; mi++)
        #pragma unroll
        for (int ni = 0; ni < 3; ni++) {
            acc[mi][ni] = __builtin_amdgcn_mfma_f32_16x16x32_f16(ah[mi], bl[ni], acc[mi][ni], 0, 0, 0);
            acc[mi][ni] = __builtin_amdgcn_mfma_f32_16x16x32_f16(al[mi], bh[ni], acc[mi][ni], 0, 0, 0);
            acc[mi][ni] = __builtin_amdgcn_mfma_f32_16x16x32_f16(ah[mi], bh[ni], acc[mi][ni], 0, 0, 0);
        }
}

template<int KD>
__device__ __forceinline__ void gemm_core32(
    const _Float16* __restrict__ A0h, const _Float16* __restrict__ A0l,
    const _Float16* __restrict__ A1h, const _Float16* __restrict__ A1l,
    const _Float16* __restrict__ Wh, const _Float16* __restrict__ Wl,
    int t0, int n0, int col, int quad, f32x4 (&acc)[2][3])
{
    f16x8 ah[2][2], al[2][2], bh[2][3], bl[2][3];
    auto loadA = [&](int k0, int s) {
        const _Float16* Ph = (KD == 384 && k0 >= 192) ? A1h : A0h;
        const _Float16* Pl = (KD == 384 && k0 >= 192) ? A1l : A0l;
        int kc = (KD == 384 && k0 >= 192) ? k0 - 192 : k0;
        #pragma unroll
        for (int mi = 0; mi < 2; mi++) {
            size_t off = (size_t)(t0 + mi * 16 + col) * DD + kc + quad * 8;
            ah[s][mi] = *(const f16x8*)&Ph[off];
            al[s][mi] = *(const f16x8*)&Pl[off];
        }
    };
    auto loadB = [&](int k0, int s) {
        #pragma unroll
        for (int ni = 0; ni < 3; ni++) {
            size_t off = (size_t)(n0 + ni * 16 + col) * KD + k0 + quad * 8;
            bh[s][ni] = *(const f16x8*)&Wh[off];
            bl[s][ni] = *(const f16x8*)&Wl[off];
        }
    };
    loadA(0, 0); loadB(0, 0);
    loadA(32, 1); loadB(32, 1);
    #pragma unroll
    for (int k0 = 0; k0 < KD; k0 += 32) {
        int s = (k0 >> 5) & 1;
        mfma_set3(ah[s], al[s], bh[s], bl[s], acc);
        if (k0 + 64 < KD) { loadA(k0 + 64, s); loadB(k0 + 64, s); }
    }
}

// ---------------------------------------------------------------------------
// Fused z-GEMM + xdbl-GEMM (K=384).
// z blocks: 32 tokens x full 192 N (4 waves share the A-tile -> L1/L2 reuse).
// xdbl blocks: 128 tokens x 48 N.
__global__ __launch_bounds__(256) void gemm_zx(
    const _Float16* __restrict__ uH, const _Float16* __restrict__ uL,
    const _Float16* __restrict__ QpH, const _Float16* __restrict__ QpL,
    const _Float16* __restrict__ KpH, const _Float16* __restrict__ KpL,
    const _Float16* __restrict__ gWh, const _Float16* __restrict__ gWl,
    const _Float16* __restrict__ dbWh, const _Float16* __restrict__ dbWl,
    const float* __restrict__ gate_b,
    _Float16* __restrict__ zsH, _Float16* __restrict__ zsL,
    float* __restrict__ dtbp, float* __restrict__ Bbp, float* __restrict__ Cbp)
{
    int tid = threadIdx.x;
    int lane = tid & 63, w = tid >> 6;
    int col = lane & 15, quad = lane >> 4;
    const int ZB = MTOK / 32;   // 1152
    bool isz = (int)blockIdx.x < ZB;
    int t0, n0;
    const _Float16 *A1h, *A1l, *Bh, *Bl;
    if (isz) {
        t0 = blockIdx.x * 32;
        n0 = w * 48;
        A1h = QpH; A1l = QpL; Bh = gWh; Bl = gWl;
    } else {
        int bx = blockIdx.x - ZB;
        t0 = bx * 128 + w * 32;
        n0 = 0;
        A1h = KpH; A1l = KpL; Bh = dbWh; Bl = dbWl;
    }
    f32x4 zv4 = {0.f, 0.f, 0.f, 0.f};
    f32x4 acc[2][3];
    #pragma unroll
    for (int mi = 0; mi < 2; mi++)
        #pragma unroll
        for (int ni = 0; ni < 3; ni++) acc[mi][ni] = zv4;
    gemm_core32<384>(uH, uL, A1h, A1l, Bh, Bl, t0, n0, col, quad, acc);
    const float osc = 1.f / (SA * SW);
    if (isz) {
        #pragma unroll
        for (int ni = 0; ni < 3; ni++) {
            int d = n0 + ni * 16 + col;
            float bv = gate_b[d];
            #pragma unroll
            for (int mi = 0; mi < 2; mi++)
                #pragma unroll
                for (int r = 0; r < 4; r++) {
                    size_t t = t0 + mi * 16 + quad * 4 + r;
                    float z = siluf(acc[mi][ni][r] * osc + bv);
                    _Float16 h = (_Float16)z;
                    zsH[t * DD + d] = h;
                    zsL[t * DD + d] = (_Float16)(z - (float)h);
                }
        }
    } else {
        #pragma unroll
        for (int ni = 0; ni < 3; ni++) {
            int d = n0 + ni * 16 + col;
            #pragma unroll
            for (int mi = 0; mi < 2; mi++)
                #pragma unroll
                for (int r = 0; r < 4; r++) {
                    size_t t = t0 + mi * 16 + quad * 4 + r;
                    float v = acc[mi][ni][r] * osc;
                    if (d < 6)       dtbp[t * 8 + d] = v;
                    else if (d < 22) Bbp[t * 16 + (d - 6)] = v;
                    else if (d < 38) Cbp[t * 16 + (d - 22)] = v;
                    else if (d < 40) dtbp[t * 8 + (d - 32)] = 0.f;
                }
        }
    }
}

// ---------------------------------------------------------------------------
// Final out-projection (K=192): block = 64 tokens x full 96 N.
__global__ __launch_bounds__(256) void gemm_out(
    const _Float16* __restrict__ yH, const _Float16* __restrict__ yL,
    const _Float16* __restrict__ oWh, const _Float16* __restrict__ oWl,
    float* __restrict__ outF)
{
    int tid = threadIdx.x;
    int lane = tid & 63, w = tid >> 6;
    int col = lane & 15, quad = lane >> 4;
    int t0 = blockIdx.x * 64 + (w & 1) * 32;
    int n0 = (w >> 1) * 48;
    f32x4 zv4 = {0.f, 0.f, 0.f, 0.f};
    f32x4 acc[2][3];
    #pragma unroll
    for (int mi = 0; mi < 2; mi++)
        #pragma unroll
        for (int ni = 0; ni < 3; ni++) acc[mi][ni] = zv4;
    gemm_core32<192>(yH, yL, nullptr, nullptr, oWh, oWl, t0, n0, col, quad, acc);
    const float osc = 1.f / (SY * SW);
    int bq = t0 / LL;
    int lb = t0 % LL;
    #pragma unroll
    for (int ni = 0; ni < 3; ni++) {
        int d = n0 + ni * 16 + col;
        #pragma unroll
        for (int mi = 0; mi < 2; mi++) {
            f32x4 v;
            #pragma unroll
            for (int r = 0; r < 4; r++) v[r] = acc[mi][ni][r] * osc;
            *(f32x4*)&outF[((size_t)(bq * 96 + d)) * LL + lb + mi * 16 + quad * 4] = v;
        }
    }
}

// ---------------------------------------------------------------------------
// Chunked selective scan. Pass 1 stores per-chunk sd (= sum of delta) and S.
__global__ __launch_bounds__(64) void scan_pass1(
    const _Float16* __restrict__ uh, const _Float16* __restrict__ ul,
    const float* __restrict__ dtb, const float* __restrict__ Bb,
    const float* __restrict__ A_log,
    const float* __restrict__ dtw, const float* __restrict__ dtbias,
    float* __restrict__ sd_ws, float* __restrict__ S_ws)
{
    int g = blockIdx.x, dblk = blockIdx.y, b = blockIdx.z;
    int d = dblk * 64 + threadIdx.x;
    size_t tbase = (size_t)b * LL + g * LC;
    float Av[NS];
    #pragma unroll
    for (int n = 0; n < NS; n++) Av[n] = -__expf(A_log[d * NS + n]);
    float w6[RR];
    #pragma unroll
    for (int r = 0; r < RR; r++) w6[r] = dtw[d * RR + r];
    float b2 = 2.f * dtbias[d];
    float h[NS];
    #pragma unroll
    for (int n = 0; n < NS; n++) h[n] = 0.f;
    float sd = 0.f;
    const _Float16* uhp = uh + tbase * DD + d;
    const _Float16* ulp = ul + tbase * DD + d;
    #pragma unroll 2
    for (int t = 0; t < LC; t++) {
        f32x4 d0 = *(const f32x4*)&dtb[(tbase + t) * 8];
        f32x4 d1 = *(const f32x4*)&dtb[(tbase + t) * 8 + 4];
        float s = b2;
        s = fmaf(d0[0], w6[0], s); s = fmaf(d0[1], w6[1], s);
        s = fmaf(d0[2], w6[2], s); s = fmaf(d0[3], w6[3], s);
        s = fmaf(d1[0], w6[4], s); s = fmaf(d1[1], w6[5], s);
        float dlt = softplusf(s);
        sd += dlt;
        float uu = ((float)uhp[(size_t)t * DD] + (float)ulp[(size_t)t * DD]) * (1.f / SA);
        float du = dlt * uu;
        f32x4 Bv[4];
        #pragma unroll
        for (int q = 0; q < 4; q++) Bv[q] = *(const f32x4*)&Bb[(tbase + t) * 16 + q * 4];
        #pragma unroll
        for (int n = 0; n < NS; n++) {
            float a = __expf(dlt * Av[n]);
            h[n] = fmaf(a, h[n], du * Bv[n >> 2][n & 3]);
        }
    }
    size_t o = ((size_t)(b * NG + g) * DD + d) * NS;
    sd_ws[(size_t)(b * NG + g) * DD + d] = sd;
    #pragma unroll
    for (int q = 0; q < 4; q++) {
        f32x4 sv;
        #pragma unroll
        for (int e = 0; e < 4; e++) sv[e] = h[q * 4 + e];
        *(f32x4*)(S_ws + o + q * 4) = sv;
    }
}

// ---------------------------------------------------------------------------
// 3-level parallel chunk-combine.
__global__ __launch_bounds__(256) void combine_a(
    const float* __restrict__ sd_ws, const float* __restrict__ S_ws,
    const float* __restrict__ A_log,
    float* __restrict__ Sg, float* __restrict__ sdg)
{
    int idx = blockIdx.x * 256 + threadIdx.x;
    int n = idx & 15;
    int d = (idx >> 4) % DD;
    int grp = (idx >> 4) / DD % NGRP;
    int b = idx / (NS * DD * NGRP);
    float Av = -__expf(A_log[d * NS + n]);
    float h = 0.f, sds = 0.f;
    #pragma unroll
    for (int j = 0; j < GSZ; j++) {
        int g = grp * GSZ + j;
        size_t cb = (size_t)(b * NG + g) * DD + d;
        float sd = sd_ws[cb];
        float a = __expf(sd * Av);
        h = fmaf(a, h, S_ws[cb * NS + n]);
        sds += sd;
    }
    size_t o = (size_t)(b * NGRP + grp) * DD + d;
    Sg[o * NS + n] = h;
    if (n == 0) sdg[o] = sds;
}

__global__ __launch_bounds__(256) void combine_b(
    const float* __restrict__ Sg, const float* __restrict__ sdg,
    const float* __restrict__ A_log, float* __restrict__ Hgrp)
{
    int idx = blockIdx.x * 256 + threadIdx.x;
    int n = idx & 15;
    int d = (idx >> 4) % DD;
    int b = idx / (NS * DD);
    float Av = -__expf(A_log[d * NS + n]);
    float h = 0.f;
    #pragma unroll
    for (int grp = 0; grp < NGRP; grp++) {
        size_t o = (size_t)(b * NGRP + grp) * DD + d;
        Hgrp[o * NS + n] = h;
        float a = __expf(sdg[o] * Av);
        h = fmaf(a, h, Sg[o * NS + n]);
    }
}

__global__ __launch_bounds__(256) void combine_c(
    const float* __restrict__ sd_ws, const float* __restrict__ S_ws,
    const float* __restrict__ Hgrp, const float* __restrict__ A_log,
    float* __restrict__ H_ws)
{
    int idx = blockIdx.x * 256 + threadIdx.x;
    int n = idx & 15;
    int d = (idx >> 4) % DD;
    int grp = (idx >> 4) / DD % NGRP;
    int b = idx / (NS * DD * NGRP);
    float Av = -__expf(A_log[d * NS + n]);
    float h = Hgrp[((size_t)(b * NGRP + grp) * DD + d) * NS + n];
    #pragma unroll
    for (int j = 0; j < GSZ; j++) {
        int g = grp * GSZ + j;
        size_t cb = (size_t)(b * NG + g) * DD + d;
        H_ws[cb * NS + n] = h;
        float a = __expf(sd_ws[cb] * Av);
        h = fmaf(a, h, S_ws[cb * NS + n]);
    }
}

// ---------------------------------------------------------------------------
__global__ __launch_bounds__(64) void scan_pass2(
    const _Float16* __restrict__ uh, const _Float16* __restrict__ ul,
    const float* __restrict__ dtb, const float* __restrict__ Bb,
    const float* __restrict__ Cb, const float* __restrict__ A_log,
    const float* __restrict__ dtw, const float* __restrict__ dtbias,
    const float* __restrict__ H_ws,
    const _Float16* __restrict__ zsH, const _Float16* __restrict__ zsL,
    const float* __restrict__ Dvec,
    _Float16* __restrict__ yh, _Float16* __restrict__ yl)
{
    int g = blockIdx.x, dblk = blockIdx.y, b = blockIdx.z;
    int d = dblk * 64 + threadIdx.x;
    size_t tbase = (size_t)b * LL + g * LC;
    float Av[NS];
    #pragma unroll
    for (int n = 0; n < NS; n++) Av[n] = -__expf(A_log[d * NS + n]);
    float w6[RR];
    #pragma unroll
    for (int r = 0; r < RR; r++) w6[r] = dtw[d * RR + r];
    float b2 = 2.f * dtbias[d];
    float h[NS];
    size_t o = ((size_t)(b * NG + g) * DD + d) * NS;
    #pragma unroll
    for (int q = 0; q < 4; q++) {
        f32x4 hv = *(const f32x4*)(H_ws + o + q * 4);
        #pragma unroll
        for (int e = 0; e < 4; e++) h[q * 4 + e] = hv[e];
    }
    float Dv = Dvec[d];
    const _Float16* uhp = uh + tbase * DD + d;
    const _Float16* ulp = ul + tbase * DD + d;
    const _Float16* zhp = zsH + tbase * DD + d;
    const _Float16* zlp = zsL + tbase * DD + d;
    _Float16* yhp = yh + tbase * DD + d;
    _Float16* ylp = yl + tbase * DD + d;
    #pragma unroll 2
    for (int t = 0; t < LC; t++) {
        f32x4 d0 = *(const f32x4*)&dtb[(tbase + t) * 8];
        f32x4 d1 = *(const f32x4*)&dtb[(tbase + t) * 8 + 4];
        float s = b2;
        s = fmaf(d0[0], w6[0], s); s = fmaf(d0[1], w6[1], s);
        s = fmaf(d0[2], w6[2], s); s = fmaf(d0[3], w6[3], s);
        s = fmaf(d1[0], w6[4], s); s = fmaf(d1[1], w6[5], s);
        float dlt = softplusf(s);
        float uu = ((float)uhp[(size_t)t * DD] + (float)ulp[(size_t)t * DD]) * (1.f / SA);
        float du = dlt * uu;
        f32x4 Bv[4], Cv[4];
        #pragma unroll
        for (int q = 0; q < 4; q++) {
            Bv[q] = *(const f32x4*)&Bb[(tbase + t) * 16 + q * 4];
            Cv[q] = *(const f32x4*)&Cb[(tbase + t) * 16 + q * 4];
        }
        float yv = 0.f;
        #pragma unroll
        for (int n = 0; n < NS; n++) {
            float a = __expf(dlt * Av[n]);
            h[n] = fmaf(a, h[n], du * Bv[n >> 2][n & 3]);
            yv = fmaf(h[n], Cv[n >> 2][n & 3], yv);
        }
        float zv = (float)zhp[(size_t)t * DD] + (float)zlp[(size_t)t * DD];
        float y = (yv + uu * Dv) * zv * SY;
        _Float16 hh = (_Float16)y;
        yhp[(size_t)t * DD] = hh;
        ylp[(size_t)t * DD] = (_Float16)(y - (float)hh);
    }
}

// ---------------------------------------------------------------------------
extern "C" void kernel_launch(void* const* d_in, const int* in_sizes, int n_in,
                              void* d_out, int out_size, void* d_ws, size_t ws_size,
                              hipStream_t stream)
{
    (void)in_sizes; (void)n_in; (void)out_size; (void)ws_size;
    const float* x        = (const float*)d_in[0];
    const float* K        = (const float*)d_in[1];
    const float* Q        = (const float*)d_in[2];
    const float* in_projw = (const float*)d_in[3];
    const float* conv_w   = (const float*)d_in[4];
    const float* conv_b   = (const float*)d_in[5];
    const float* k_ln_g   = (const float*)d_in[6];
    const float* k_ln_b   = (const float*)d_in[7];
    const float* k_w      = (const float*)d_in[8];
    const float* k_b      = (const float*)d_in[9];
    const float* q_ln_g   = (const float*)d_in[10];
    const float* q_ln_b   = (const float*)d_in[11];
    const float* q_w      = (const float*)d_in[12];
    const float* q_b      = (const float*)d_in[13];
    const float* dtbc_w   = (const float*)d_in[14];
    const float* dt_w     = (const float*)d_in[15];
    const float* dt_b     = (const float*)d_in[16];
    const float* gate_w   = (const float*)d_in[17];
    const float* gate_b   = (const float*)d_in[18];
    const float* A_log    = (const float*)d_in[19];
    const float* Dvec     = (const float*)d_in[20];
    const float* out_w    = (const float*)d_in[21];
    float* out = (float*)d_out;

    const size_t S0 = (size_t)MTOK * DD;
    char* base = (char*)d_ws;
    size_t off = 0;
    auto alloc = [&](size_t bytes) {
        char* p = base + off;
        off += (bytes + 255) & ~(size_t)255;
        return p;
    };
    float*     xin   = (float*)alloc(S0 * 4);
    _Float16*  zsH   = (_Float16*)alloc(S0 * 2);
    _Float16*  zsL   = (_Float16*)alloc(S0 * 2);
    _Float16*  uH    = (_Float16*)alloc(S0 * 2);
    _Float16*  uL    = (_Float16*)alloc(S0 * 2);
    _Float16*  KpH   = (_Float16*)alloc(S0 * 2);         // reused as yH
    _Float16*  KpL   = (_Float16*)alloc(S0 * 2);         // reused as yL
    _Float16*  QpH   = (_Float16*)alloc(S0 * 2);
    _Float16*  QpL   = (_Float16*)alloc(S0 * 2);
    float*     dtbB  = (float*)alloc((size_t)MTOK * 8 * 4);
    float*     Bb    = (float*)alloc((size_t)MTOK * 16 * 4);
    float*     Cb    = (float*)alloc((size_t)MTOK * 16 * 4);
    float*     gwK   = (float*)alloc(DD * CD * 4);
    float*     gwQ   = (float*)alloc(DD * CD * 4);
    float*     wsumK = (float*)alloc(DD * 4);
    float*     biasK = (float*)alloc(DD * 4);
    float*     wsumQ = (float*)alloc(DD * 4);
    float*     biasQ = (float*)alloc(DD * 4);
    _Float16*  ipWh  = (_Float16*)alloc(DD * CD * 2);
    _Float16*  ipWl  = (_Float16*)alloc(DD * CD * 2);
    _Float16*  kWh   = (_Float16*)alloc(DD * CD * 2);
    _Float16*  kWl   = (_Float16*)alloc(DD * CD * 2);
    _Float16*  qWh   = (_Float16*)alloc(DD * CD * 2);
    _Float16*  qWl   = (_Float16*)alloc(DD * CD * 2);
    _Float16*  dbWh  = (_Float16*)alloc(48 * 384 * 2);
    _Float16*  dbWl  = (_Float16*)alloc(48 * 384 * 2);
    _Float16*  gWh   = (_Float16*)alloc(DD * 384 * 2);
    _Float16*  gWl   = (_Float16*)alloc(DD * 384 * 2);
    _Float16*  oWh   = (_Float16*)alloc(96 * DD * 2);
    _Float16*  oWl   = (_Float16*)alloc(96 * DD * 2);
    float*     sd_ws = (float*)alloc((size_t)BZ * NG * DD * 4);
    float*     S_ws  = (float*)alloc((size_t)BZ * NG * DD * NS * 4);
    float*     H_ws  = (float*)alloc((size_t)BZ * NG * DD * NS * 4);
    float*     Sg    = (float*)alloc((size_t)BZ * NGRP * DD * NS * 4);
    float*     sdg   = (float*)alloc((size_t)BZ * NGRP * DD * 4);
    float*     Hgrp  = (float*)alloc((size_t)BZ * NGRP * DD * NS * 4);
    _Float16* yH = KpH;
    _Float16* yL = KpL;

    prep_kernel<<<dim3(DD, 2), 96, 0, stream>>>(k_ln_g, k_ln_b, k_w, k_b,
        q_ln_g, q_ln_b, q_w, q_b, gwK, wsumK, biasK, gwQ, wsumQ, biasQ);
    {
        const int total = 18432 * 5 + 73728;
        split_all_kernel<<<(total + 255) / 256, 256, 0, stream>>>(
            in_projw, gwK, gwQ, dtbc_w, gate_w, out_w,
            ipWh, ipWl, kWh, kWl, qWh, qWl, dbWh, dbWl, gWh, gWl, oWh, oWl);
    }

    mfma_projCH3<<<dim3(LL / 64, BZ, 3), 256, 0, stream>>>(
        x, K, Q, ipWh, ipWl, kWh, kWl, qWh, qWl,
        wsumK, biasK, wsumQ, biasQ, xin, KpH, KpL, QpH, QpL);
    conv_kernel<<<(MTOK / 4) * (DD / 4) / 256, 256, 0, stream>>>(xin, conv_w, conv_b, uH, uL);
    gemm_zx<<<MTOK / 32 + MTOK / 128, 256, 0, stream>>>(
        uH, uL, QpH, QpL, KpH, KpL, gWh, gWl, dbWh, dbWl, gate_b,
        zsH, zsL, dtbB, Bb, Cb);
    scan_pass1<<<dim3(NG, DD / 64, BZ), 64, 0, stream>>>(
        uH, uL, dtbB, Bb, A_log, dt_w, dt_b, sd_ws, S_ws);
    combine_a<<<(BZ * NGRP * DD * NS) / 256, 256, 0, stream>>>(sd_ws, S_ws, A_log, Sg, sdg);
    combine_b<<<(BZ * DD * NS) / 256, 256, 0, stream>>>(Sg, sdg, A_log, Hgrp);
    combine_c<<<(BZ * NGRP * DD * NS) / 256, 256, 0, stream>>>(sd_ws, S_ws, Hgrp, A_log, H_ws);
    scan_pass2<<<dim3(NG, DD / 64, BZ), 64, 0, stream>>>(
        uH, uL, dtbB, Bb, Cb, A_log, dt_w, dt_b, H_ws, zsH, zsL, Dvec, yH, yL);
    gemm_out<<<MTOK / 64, 256, 0, stream>>>(yH, yL, oWh, oWl, out);
}

// Round 8
// 386.655 us; speedup vs baseline: 1.1249x; 1.1249x over previous
//
#include <hip/hip_runtime.h>
#include <cstdint>
#include <cstddef>

#define BZ 4
#define CD 96
#define LL 9216
#define DD 192
#define NS 16
#define RR 6
#define LC 32
#define NG 288
#define NGRP 16
#define GSZ 18
#define MTOK (BZ * LL)
#define ZBLK (MTOK / 128)

#define SA 256.0f
#define SW 1024.0f
#define SY 16.0f

typedef _Float16 f16x8 __attribute__((ext_vector_type(8)));
typedef _Float16 f16x4 __attribute__((ext_vector_type(4)));
typedef float f32x4 __attribute__((ext_vector_type(4)));

__device__ __forceinline__ float siluf(float x) {
    return x / (1.f + __expf(-x));
}
__device__ __forceinline__ float softplusf(float x) {
    return fmaxf(x, 0.f) + log1pf(__expf(-fabsf(x)));
}

// ---------------------------------------------------------------------------
__global__ void prep_kernel(const float* kg, const float* kb, const float* kw, const float* kbias,
                            const float* qg, const float* qb, const float* qw, const float* qbias,
                            float* gwK, float* wsumK, float* biasK,
                            float* gwQ, float* wsumQ, float* biasQ) {
    int d = blockIdx.x;
    const float* g  = blockIdx.y ? qg : kg;
    const float* lb = blockIdx.y ? qb : kb;
    const float* w  = blockIdx.y ? qw : kw;
    const float* b2 = blockIdx.y ? qbias : kbias;
    float* gw = blockIdx.y ? gwQ : gwK;
    float* wsv = blockIdx.y ? wsumQ : wsumK;
    float* bv = blockIdx.y ? biasQ : biasK;
    int c = threadIdx.x;
    __shared__ float s1[96], s2[96];
    float wv = w[d * 96 + c];
    float gv = g[c] * wv;
    gw[d * 96 + c] = gv;
    s1[c] = gv;
    s2[c] = lb[c] * wv;
    __syncthreads();
    if (c < 32) { s1[c] += s1[c + 64]; s2[c] += s2[c + 64]; }
    __syncthreads();
    for (int s = 32; s >= 1; s >>= 1) {
        if (c < s) { s1[c] += s1[c + s]; s2[c] += s2[c + s]; }
        __syncthreads();
    }
    if (c == 0) { wsv[d] = s1[0]; bv[d] = b2[d] + s2[0]; }
}

// ---------------------------------------------------------------------------
__global__ __launch_bounds__(256) void split_all_kernel(
    const float* __restrict__ s0, const float* __restrict__ s1, const float* __restrict__ s2,
    const float* __restrict__ s3, const float* __restrict__ s4, const float* __restrict__ s5,
    _Float16* __restrict__ d0h, _Float16* __restrict__ d0l,
    _Float16* __restrict__ d1h, _Float16* __restrict__ d1l,
    _Float16* __restrict__ d2h, _Float16* __restrict__ d2l,
    _Float16* __restrict__ d3h, _Float16* __restrict__ d3l,
    _Float16* __restrict__ d4h, _Float16* __restrict__ d4l,
    _Float16* __restrict__ d5h, _Float16* __restrict__ d5l)
{
    int idx = blockIdx.x * 256 + threadIdx.x;
    const int C0 = 18432, C1 = 18432, C2 = 18432, C3 = 18432, C4 = 73728, C5 = 18432;
    const float* src; _Float16* dh; _Float16* dl; int i; bool pad = false;
    if (idx < C0) { src = s0; dh = d0h; dl = d0l; i = idx; }
    else if (idx < C0 + C1) { src = s1; dh = d1h; dl = d1l; i = idx - C0; }
    else if (idx < C0 + C1 + C2) { src = s2; dh = d2h; dl = d2l; i = idx - C0 - C1; }
    else if (idx < C0 + C1 + C2 + C3) {
        src = s3; dh = d3h; dl = d3l; i = idx - C0 - C1 - C2;
        pad = (i / 384) >= 38;   // dtbc_w: 38 real rows padded to 48
    }
    else if (idx < C0 + C1 + C2 + C3 + C4) { src = s4; dh = d4h; dl = d4l; i = idx - C0 - C1 - C2 - C3; }
    else if (idx < C0 + C1 + C2 + C3 + C4 + C5) { src = s5; dh = d5h; dl = d5l; i = idx - C0 - C1 - C2 - C3 - C4; }
    else return;
    float v = pad ? 0.f : src[i] * SW;
    _Float16 h = (_Float16)v;
    dh[i] = h;
    dl[i] = (_Float16)(v - (float)h);
}

// ---------------------------------------------------------------------------
// Merged MFMA projection (x / K / Q by blockIdx.z), K=96, N=192.
// LN stats accumulated inside the staging loop.
__global__ __launch_bounds__(256) void mfma_projCH3(
    const float* __restrict__ xA, const float* __restrict__ KA, const float* __restrict__ QA,
    const _Float16* __restrict__ ipWh, const _Float16* __restrict__ ipWl,
    const _Float16* __restrict__ kWh, const _Float16* __restrict__ kWl,
    const _Float16* __restrict__ qWh, const _Float16* __restrict__ qWl,
    const float* __restrict__ wsumK, const float* __restrict__ biasK,
    const float* __restrict__ wsumQ, const float* __restrict__ biasQ,
    float* __restrict__ xin,
    _Float16* __restrict__ KpH, _Float16* __restrict__ KpL,
    _Float16* __restrict__ QpH, _Float16* __restrict__ QpL)
{
    int which = blockIdx.z;
    const float* A = which == 0 ? xA : (which == 1 ? KA : QA);
    const _Float16* Wh = which == 0 ? ipWh : (which == 1 ? kWh : qWh);
    const _Float16* Wl = which == 0 ? ipWl : (which == 1 ? kWl : qWl);
    const float* wsum = which == 1 ? wsumK : wsumQ;
    const float* biasv = which == 1 ? biasK : biasQ;
    _Float16* outH = which == 1 ? KpH : QpH;
    _Float16* outL = which == 1 ? KpL : QpL;
    bool LN = which != 0;

    int b = blockIdx.y;
    int l0 = blockIdx.x * 64;
    int tid = threadIdx.x;
    int lane = tid & 63, w = tid >> 6;

    __shared__ __align__(16) _Float16 Ah[64 * 104];
    __shared__ __align__(16) _Float16 Al[64 * 104];
    __shared__ float sm[64], siv[64];
    __shared__ float red1[256], red2[256];

    {
        float s = 0.f, ss = 0.f;
        #pragma unroll 4
        for (int i = tid; i < 96 * 64; i += 256) {
            int c = i >> 6, l = i & 63;
            float a = A[((size_t)b * CD + c) * LL + l0 + l];
            float v = a * SA;
            _Float16 h = (_Float16)v;
            Ah[l * 104 + c] = h;
            Al[l * 104 + c] = (_Float16)(v - (float)h);
            s += a; ss += a * a;
        }
        if (LN) { red1[tid] = s; red2[tid] = ss; }
    }
    __syncthreads();
    if (LN && tid < 64) {
        float s4 = red1[tid] + red1[tid + 64] + red1[tid + 128] + red1[tid + 192];
        float q4 = red2[tid] + red2[tid + 64] + red2[tid + 128] + red2[tid + 192];
        float m = s4 / 96.f;
        sm[tid] = m;
        siv[tid] = rsqrtf(fmaxf(q4 / 96.f - m * m, 0.f) + 1e-5f);
    }
    if (LN) __syncthreads();

    int col = lane & 15, quad = lane >> 4;
    int n0 = w * 48;
    f32x4 zv4 = {0.f, 0.f, 0.f, 0.f};
    f32x4 acc[4][3];
    #pragma unroll
    for (int mi = 0; mi < 4; mi++)
        #pragma unroll
        for (int ni = 0; ni < 3; ni++) acc[mi][ni] = zv4;
    for (int c0 = 0; c0 < 96; c0 += 32) {
        f16x8 afh[4], afl[4], bfh[3], bfl[3];
        #pragma unroll
        for (int mi = 0; mi < 4; mi++) {
            int off = (16 * mi + col) * 104 + c0 + quad * 8;
            afh[mi] = *(const f16x8*)&Ah[off];
            afl[mi] = *(const f16x8*)&Al[off];
        }
        #pragma unroll
        for (int ni = 0; ni < 3; ni++) {
            size_t off = (size_t)(n0 + ni * 16 + col) * 96 + c0 + quad * 8;
            bfh[ni] = *(const f16x8*)&Wh[off];
            bfl[ni] = *(const f16x8*)&Wl[off];
        }
        #pragma unroll
        for (int mi = 0; mi < 4; mi++)
            #pragma unroll
            for (int ni = 0; ni < 3; ni++) {
                acc[mi][ni] = __builtin_amdgcn_mfma_f32_16x16x32_f16(afh[mi], bfl[ni], acc[mi][ni], 0, 0, 0);
                acc[mi][ni] = __builtin_amdgcn_mfma_f32_16x16x32_f16(afl[mi], bfh[ni], acc[mi][ni], 0, 0, 0);
                acc[mi][ni] = __builtin_amdgcn_mfma_f32_16x16x32_f16(afh[mi], bfh[ni], acc[mi][ni], 0, 0, 0);
            }
    }
    const float isc = 1.f / (SA * SW);
    if (LN) {
        #pragma unroll
        for (int ni = 0; ni < 3; ni++) {
            int d = n0 + ni * 16 + col;
            float wsv = wsum[d];
            float bvv = biasv[d];
            #pragma unroll
            for (int mi = 0; mi < 4; mi++)
                #pragma unroll
                for (int r = 0; r < 4; r++) {
                    int tl = mi * 16 + quad * 4 + r;
                    float v = acc[mi][ni][r] * isc;
                    size_t t = (size_t)b * LL + l0 + tl;
                    v = (v - sm[tl] * wsv) * siv[tl] + bvv;
                    v = siluf(v) * SA;
                    _Float16 h = (_Float16)v;
                    outH[t * DD + d] = h;
                    outL[t * DD + d] = (_Float16)(v - (float)h);
                }
        }
    } else {
        #pragma unroll
        for (int ni = 0; ni < 3; ni++) {
            int d = n0 + ni * 16 + col;
            #pragma unroll
            for (int mi = 0; mi < 4; mi++)
                #pragma unroll
                for (int r = 0; r < 4; r++) {
                    int tl = mi * 16 + quad * 4 + r;
                    size_t t = (size_t)b * LL + l0 + tl;
                    xin[t * DD + d] = acc[mi][ni][r] * isc;
                }
        }
    }
}

// ---------------------------------------------------------------------------
__global__ __launch_bounds__(256) void conv_kernel(const float* __restrict__ xin,
        const float* __restrict__ cw, const float* __restrict__ cb,
        _Float16* __restrict__ uh, _Float16* __restrict__ ul)
{
    int gid = blockIdx.x * 256 + threadIdx.x;
    int dg = gid % (DD / 4);
    int tg = gid / (DD / 4);
    int b = tg / (LL / 4);
    int l0 = (tg % (LL / 4)) * 4;
    size_t rowbase = ((size_t)b * LL + l0) * DD + dg * 4;
    f32x4 r[7];
    #pragma unroll
    for (int j = 0; j < 7; j++) {
        int l = l0 - 3 + j;
        f32x4 z4 = {0.f, 0.f, 0.f, 0.f};
        r[j] = (l >= 0) ? *(const f32x4*)&xin[rowbase + (size_t)(j - 3) * DD] : z4;
    }
    float cwv[4][4], cb4[4];
    #pragma unroll
    for (int e = 0; e < 4; e++) {
        cb4[e] = cb[dg * 4 + e];
        #pragma unroll
        for (int j = 0; j < 4; j++) cwv[e][j] = cw[(dg * 4 + e) * 4 + j];
    }
    #pragma unroll
    for (int tt = 0; tt < 4; tt++) {
        f16x4 oh, ol;
        #pragma unroll
        for (int e = 0; e < 4; e++) {
            float s = cb4[e];
            #pragma unroll
            for (int j = 0; j < 4; j++) s = fmaf(cwv[e][j], r[tt + j][e], s);
            float u = siluf(s) * SA;
            _Float16 h = (_Float16)u;
            oh[e] = h;
            ol[e] = (_Float16)(u - (float)h);
        }
        *(f16x4*)&uh[rowbase + (size_t)tt * DD] = oh;
        *(f16x4*)&ul[rowbase + (size_t)tt * DD] = ol;
    }
}

// ---------------------------------------------------------------------------
// LDS-tiled fused z-GEMM + xdbl-GEMM (K=384, BK=32, 12 iters).
// z blocks (blockIdx < ZBLK): 128 tokens x 192 N, wave = 64 tok x 96 N.
// xdbl blocks: 128 tokens x 48 N, wave = 32 tok x 48 N.
// LDS tiles padded to stride 40 f16 (80 B, 16B-aligned, 2-way conflicts only).
__global__ __launch_bounds__(256) void gemm_zx(
    const _Float16* __restrict__ uH, const _Float16* __restrict__ uL,
    const _Float16* __restrict__ QpH, const _Float16* __restrict__ QpL,
    const _Float16* __restrict__ KpH, const _Float16* __restrict__ KpL,
    const _Float16* __restrict__ gWh, const _Float16* __restrict__ gWl,
    const _Float16* __restrict__ dbWh, const _Float16* __restrict__ dbWl,
    const float* __restrict__ gate_b,
    _Float16* __restrict__ zsH, _Float16* __restrict__ zsL,
    float* __restrict__ dtbp, float* __restrict__ Bbp, float* __restrict__ Cbp)
{
    __shared__ __align__(16) _Float16 Ah_s[128 * 40];
    __shared__ __align__(16) _Float16 Al_s[128 * 40];
    __shared__ __align__(16) _Float16 Wh_s[192 * 40];
    __shared__ __align__(16) _Float16 Wl_s[192 * 40];
    int tid = threadIdx.x;
    int lane = tid & 63, w = tid >> 6;
    int col = lane & 15, quad = lane >> 4;
    bool isz = (int)blockIdx.x < ZBLK;
    int t0 = (isz ? blockIdx.x : blockIdx.x - ZBLK) * 128;
    const _Float16* A1h = isz ? QpH : KpH;
    const _Float16* A1l = isz ? QpL : KpL;
    const _Float16* Bh  = isz ? gWh : dbWh;
    const _Float16* Bl  = isz ? gWl : dbWl;
    const float osc = 1.f / (SA * SW);

    if (isz) {
        int m0 = (w & 1) * 64;
        int n0 = (w >> 1) * 96;
        f32x4 zv4 = {0.f, 0.f, 0.f, 0.f};
        f32x4 acc[4][6];
        #pragma unroll
        for (int mi = 0; mi < 4; mi++)
            #pragma unroll
            for (int ni = 0; ni < 6; ni++) acc[mi][ni] = zv4;
        for (int k0 = 0; k0 < 384; k0 += 32) {
            const _Float16* Asrch = (k0 >= 192) ? A1h : uH;
            const _Float16* Asrcl = (k0 >= 192) ? A1l : uL;
            int kc = (k0 >= 192) ? k0 - 192 : k0;
            __syncthreads();
            #pragma unroll
            for (int j = 0; j < 4; j++) {       // A: 1024 chunks of 16B
                int c = tid + 256 * j;
                int pl = c >> 9;
                int r = (c >> 2) & 127;
                int p = c & 3;
                const _Float16* src = pl ? Asrcl : Asrch;
                _Float16* dst = pl ? Al_s : Ah_s;
                *(f16x8*)&dst[r * 40 + p * 8] =
                    *(const f16x8*)&src[(size_t)(t0 + r) * DD + kc + p * 8];
            }
            #pragma unroll
            for (int j = 0; j < 6; j++) {       // W: 1536 chunks
                int c = tid + 256 * j;
                int pl = c >= 768 ? 1 : 0;
                int cc = pl ? c - 768 : c;
                int r = cc >> 2, p = cc & 3;
                const _Float16* src = pl ? Bl : Bh;
                _Float16* dst = pl ? Wl_s : Wh_s;
                *(f16x8*)&dst[r * 40 + p * 8] =
                    *(const f16x8*)&src[(size_t)r * 384 + k0 + p * 8];
            }
            __syncthreads();
            f16x8 afh[4], afl[4];
            #pragma unroll
            for (int mi = 0; mi < 4; mi++) {
                int r = m0 + mi * 16 + col;
                afh[mi] = *(const f16x8*)&Ah_s[r * 40 + quad * 8];
                afl[mi] = *(const f16x8*)&Al_s[r * 40 + quad * 8];
            }
            #pragma unroll
            for (int ni = 0; ni < 6; ni++) {
                int r = n0 + ni * 16 + col;
                f16x8 bfh = *(const f16x8*)&Wh_s[r * 40 + quad * 8];
                f16x8 bfl = *(const f16x8*)&Wl_s[r * 40 + quad * 8];
                #pragma unroll
                for (int mi = 0; mi < 4; mi++) {
                    acc[mi][ni] = __builtin_amdgcn_mfma_f32_16x16x32_f16(afh[mi], bfl, acc[mi][ni], 0, 0, 0);
                    acc[mi][ni] = __builtin_amdgcn_mfma_f32_16x16x32_f16(afl[mi], bfh, acc[mi][ni], 0, 0, 0);
                    acc[mi][ni] = __builtin_amdgcn_mfma_f32_16x16x32_f16(afh[mi], bfh, acc[mi][ni], 0, 0, 0);
                }
            }
        }
        #pragma unroll
        for (int ni = 0; ni < 6; ni++) {
            int d = n0 + ni * 16 + col;
            float bv = gate_b[d];
            #pragma unroll
            for (int mi = 0; mi < 4; mi++)
                #pragma unroll
                for (int r = 0; r < 4; r++) {
                    size_t t = t0 + m0 + mi * 16 + quad * 4 + r;
                    float z = siluf(acc[mi][ni][r] * osc + bv);
                    _Float16 h = (_Float16)z;
                    zsH[t * DD + d] = h;
                    zsL[t * DD + d] = (_Float16)(z - (float)h);
                }
        }
    } else {
        int m0 = w * 32;
        f32x4 zv4 = {0.f, 0.f, 0.f, 0.f};
        f32x4 acc[2][3];
        #pragma unroll
        for (int mi = 0; mi < 2; mi++)
            #pragma unroll
            for (int ni = 0; ni < 3; ni++) acc[mi][ni] = zv4;
        for (int k0 = 0; k0 < 384; k0 += 32) {
            const _Float16* Asrch = (k0 >= 192) ? A1h : uH;
            const _Float16* Asrcl = (k0 >= 192) ? A1l : uL;
            int kc = (k0 >= 192) ? k0 - 192 : k0;
            __syncthreads();
            #pragma unroll
            for (int j = 0; j < 4; j++) {       // A: 1024 chunks
                int c = tid + 256 * j;
                int pl = c >> 9;
                int r = (c >> 2) & 127;
                int p = c & 3;
                const _Float16* src = pl ? Asrcl : Asrch;
                _Float16* dst = pl ? Al_s : Ah_s;
                *(f16x8*)&dst[r * 40 + p * 8] =
                    *(const f16x8*)&src[(size_t)(t0 + r) * DD + kc + p * 8];
            }
            {                                    // W: 48 rows -> 384 chunks
                int c = tid;
                if (c < 384) {
                    int pl = c >= 192 ? 1 : 0;
                    int cc = pl ? c - 192 : c;
                    int r = cc >> 2, p = cc & 3;
                    const _Float16* src = pl ? Bl : Bh;
                    _Float16* dst = pl ? Wl_s : Wh_s;
                    *(f16x8*)&dst[r * 40 + p * 8] =
                        *(const f16x8*)&src[(size_t)r * 384 + k0 + p * 8];
                }
                c = tid + 256;
                if (c < 384) {
                    int cc = c - 192;
                    int r = cc >> 2, p = cc & 3;
                    *(f16x8*)&Wl_s[r * 40 + p * 8] =
                        *(const f16x8*)&Bl[(size_t)r * 384 + k0 + p * 8];
                }
            }
            __syncthreads();
            f16x8 afh[2], afl[2];
            #pragma unroll
            for (int mi = 0; mi < 2; mi++) {
                int r = m0 + mi * 16 + col;
                afh[mi] = *(const f16x8*)&Ah_s[r * 40 + quad * 8];
                afl[mi] = *(const f16x8*)&Al_s[r * 40 + quad * 8];
            }
            #pragma unroll
            for (int ni = 0; ni < 3; ni++) {
                int r = ni * 16 + col;
                f16x8 bfh = *(const f16x8*)&Wh_s[r * 40 + quad * 8];
                f16x8 bfl = *(const f16x8*)&Wl_s[r * 40 + quad * 8];
                #pragma unroll
                for (int mi = 0; mi < 2; mi++) {
                    acc[mi][ni] = __builtin_amdgcn_mfma_f32_16x16x32_f16(afh[mi], bfl, acc[mi][ni], 0, 0, 0);
                    acc[mi][ni] = __builtin_amdgcn_mfma_f32_16x16x32_f16(afl[mi], bfh, acc[mi][ni], 0, 0, 0);
                    acc[mi][ni] = __builtin_amdgcn_mfma_f32_16x16x32_f16(afh[mi], bfh, acc[mi][ni], 0, 0, 0);
                }
            }
        }
        #pragma unroll
        for (int ni = 0; ni < 3; ni++) {
            int d = ni * 16 + col;
            #pragma unroll
            for (int mi = 0; mi < 2; mi++)
                #pragma unroll
                for (int r = 0; r < 4; r++) {
                    size_t t = t0 + m0 + mi * 16 + quad * 4 + r;
                    float v = acc[mi][ni][r] * osc;
                    if (d < 6)       dtbp[t * 8 + d] = v;
                    else if (d < 22) Bbp[t * 16 + (d - 6)] = v;
                    else if (d < 38) Cbp[t * 16 + (d - 22)] = v;
                    else if (d < 40) dtbp[t * 8 + (d - 32)] = 0.f;
                }
        }
    }
}

// ---------------------------------------------------------------------------
// Pipelined 32tok x 48n wave-tile GEMM core (direct-from-global; used by out).
__device__ __forceinline__ void mfma_set3(
    const f16x8 (&ah)[2], const f16x8 (&al)[2],
    const f16x8 (&bh)[3], const f16x8 (&bl)[3], f32x4 (&acc)[2][3])
{
    #pragma unroll
    for (int mi = 0; mi < 2; mi++)
        #pragma unroll
        for (int ni = 0; ni < 3; ni++) {
            acc[mi][ni] = __builtin_amdgcn_mfma_f32_16x16x32_f16(ah[mi], bl[ni], acc[mi][ni], 0, 0, 0);
            acc[mi][ni] = __builtin_amdgcn_mfma_f32_16x16x32_f16(al[mi], bh[ni], acc[mi][ni], 0, 0, 0);
            acc[mi][ni] = __builtin_amdgcn_mfma_f32_16x16x32_f16(ah[mi], bh[ni], acc[mi][ni], 0, 0, 0);
        }
}

template<int KD>
__device__ __forceinline__ void gemm_core32(
    const _Float16* __restrict__ A0h, const _Float16* __restrict__ A0l,
    const _Float16* __restrict__ Wh, const _Float16* __restrict__ Wl,
    int t0, int n0, int col, int quad, f32x4 (&acc)[2][3])
{
    f16x8 ah[2][2], al[2][2], bh[2][3], bl[2][3];
    auto loadA = [&](int k0, int s) {
        #pragma unroll
        for (int mi = 0; mi < 2; mi++) {
            size_t off = (size_t)(t0 + mi * 16 + col) * DD + k0 + quad * 8;
            ah[s][mi] = *(const f16x8*)&A0h[off];
            al[s][mi] = *(const f16x8*)&A0l[off];
        }
    };
    auto loadB = [&](int k0, int s) {
        #pragma unroll
        for (int ni = 0; ni < 3; ni++) {
            size_t off = (size_t)(n0 + ni * 16 + col) * KD + k0 + quad * 8;
            bh[s][ni] = *(const f16x8*)&Wh[off];
            bl[s][ni] = *(const f16x8*)&Wl[off];
        }
    };
    loadA(0, 0); loadB(0, 0);
    loadA(32, 1); loadB(32, 1);
    #pragma unroll
    for (int k0 = 0; k0 < KD; k0 += 32) {
        int s = (k0 >> 5) & 1;
        mfma_set3(ah[s], al[s], bh[s], bl[s], acc);
        if (k0 + 64 < KD) { loadA(k0 + 64, s); loadB(k0 + 64, s); }
    }
}

// ---------------------------------------------------------------------------
// Final out-projection (K=192): block = 64 tokens x full 96 N.
__global__ __launch_bounds__(256) void gemm_out(
    const _Float16* __restrict__ yH, const _Float16* __restrict__ yL,
    const _Float16* __restrict__ oWh, const _Float16* __restrict__ oWl,
    float* __restrict__ outF)
{
    int tid = threadIdx.x;
    int lane = tid & 63, w = tid >> 6;
    int col = lane & 15, quad = lane >> 4;
    int t0 = blockIdx.x * 64 + (w & 1) * 32;
    int n0 = (w >> 1) * 48;
    f32x4 zv4 = {0.f, 0.f, 0.f, 0.f};
    f32x4 acc[2][3];
    #pragma unroll
    for (int mi = 0; mi < 2; mi++)
        #pragma unroll
        for (int ni = 0; ni < 3; ni++) acc[mi][ni] = zv4;
    gemm_core32<192>(yH, yL, oWh, oWl, t0, n0, col, quad, acc);
    const float osc = 1.f / (SY * SW);
    int bq = t0 / LL;
    int lb = t0 % LL;
    #pragma unroll
    for (int ni = 0; ni < 3; ni++) {
        int d = n0 + ni * 16 + col;
        #pragma unroll
        for (int mi = 0; mi < 2; mi++) {
            f32x4 v;
            #pragma unroll
            for (int r = 0; r < 4; r++) v[r] = acc[mi][ni][r] * osc;
            *(f32x4*)&outF[((size_t)(bq * 96 + d)) * LL + lb + mi * 16 + quad * 4] = v;
        }
    }
}

// ---------------------------------------------------------------------------
// Chunked selective scan. Pass 1 stores per-chunk sd (= sum of delta) and S.
__global__ __launch_bounds__(64) void scan_pass1(
    const _Float16* __restrict__ uh, const _Float16* __restrict__ ul,
    const float* __restrict__ dtb, const float* __restrict__ Bb,
    const float* __restrict__ A_log,
    const float* __restrict__ dtw, const float* __restrict__ dtbias,
    float* __restrict__ sd_ws, float* __restrict__ S_ws)
{
    int g = blockIdx.x, dblk = blockIdx.y, b = blockIdx.z;
    int d = dblk * 64 + threadIdx.x;
    size_t tbase = (size_t)b * LL + g * LC;
    float Av[NS];
    #pragma unroll
    for (int n = 0; n < NS; n++) Av[n] = -__expf(A_log[d * NS + n]);
    float w6[RR];
    #pragma unroll
    for (int r = 0; r < RR; r++) w6[r] = dtw[d * RR + r];
    float b2 = 2.f * dtbias[d];
    float h[NS];
    #pragma unroll
    for (int n = 0; n < NS; n++) h[n] = 0.f;
    float sd = 0.f;
    const _Float16* uhp = uh + tbase * DD + d;
    const _Float16* ulp = ul + tbase * DD + d;
    #pragma unroll 2
    for (int t = 0; t < LC; t++) {
        f32x4 d0 = *(const f32x4*)&dtb[(tbase + t) * 8];
        f32x4 d1 = *(const f32x4*)&dtb[(tbase + t) * 8 + 4];
        float s = b2;
        s = fmaf(d0[0], w6[0], s); s = fmaf(d0[1], w6[1], s);
        s = fmaf(d0[2], w6[2], s); s = fmaf(d0[3], w6[3], s);
        s = fmaf(d1[0], w6[4], s); s = fmaf(d1[1], w6[5], s);
        float dlt = softplusf(s);
        sd += dlt;
        float uu = ((float)uhp[(size_t)t * DD] + (float)ulp[(size_t)t * DD]) * (1.f / SA);
        float du = dlt * uu;
        f32x4 Bv[4];
        #pragma unroll
        for (int q = 0; q < 4; q++) Bv[q] = *(const f32x4*)&Bb[(tbase + t) * 16 + q * 4];
        #pragma unroll
        for (int n = 0; n < NS; n++) {
            float a = __expf(dlt * Av[n]);
            h[n] = fmaf(a, h[n], du * Bv[n >> 2][n & 3]);
        }
    }
    size_t o = ((size_t)(b * NG + g) * DD + d) * NS;
    sd_ws[(size_t)(b * NG + g) * DD + d] = sd;
    #pragma unroll
    for (int q = 0; q < 4; q++) {
        f32x4 sv;
        #pragma unroll
        for (int e = 0; e < 4; e++) sv[e] = h[q * 4 + e];
        *(f32x4*)(S_ws + o + q * 4) = sv;
    }
}

// ---------------------------------------------------------------------------
// 3-level parallel chunk-combine.
__global__ __launch_bounds__(256) void combine_a(
    const float* __restrict__ sd_ws, const float* __restrict__ S_ws,
    const float* __restrict__ A_log,
    float* __restrict__ Sg, float* __restrict__ sdg)
{
    int idx = blockIdx.x * 256 + threadIdx.x;
    int n = idx & 15;
    int d = (idx >> 4) % DD;
    int grp = (idx >> 4) / DD % NGRP;
    int b = idx / (NS * DD * NGRP);
    float Av = -__expf(A_log[d * NS + n]);
    float h = 0.f, sds = 0.f;
    #pragma unroll
    for (int j = 0; j < GSZ; j++) {
        int g = grp * GSZ + j;
        size_t cb = (size_t)(b * NG + g) * DD + d;
        float sd = sd_ws[cb];
        float a = __expf(sd * Av);
        h = fmaf(a, h, S_ws[cb * NS + n]);
        sds += sd;
    }
    size_t o = (size_t)(b * NGRP + grp) * DD + d;
    Sg[o * NS + n] = h;
    if (n == 0) sdg[o] = sds;
}

__global__ __launch_bounds__(256) void combine_b(
    const float* __restrict__ Sg, const float* __restrict__ sdg,
    const float* __restrict__ A_log, float* __restrict__ Hgrp)
{
    int idx = blockIdx.x * 256 + threadIdx.x;
    int n = idx & 15;
    int d = (idx >> 4) % DD;
    int b = idx / (NS * DD);
    float Av = -__expf(A_log[d * NS + n]);
    float h = 0.f;
    #pragma unroll
    for (int grp = 0; grp < NGRP; grp++) {
        size_t o = (size_t)(b * NGRP + grp) * DD + d;
        Hgrp[o * NS + n] = h;
        float a = __expf(sdg[o] * Av);
        h = fmaf(a, h, Sg[o * NS + n]);
    }
}

__global__ __launch_bounds__(256) void combine_c(
    const float* __restrict__ sd_ws, const float* __restrict__ S_ws,
    const float* __restrict__ Hgrp, const float* __restrict__ A_log,
    float* __restrict__ H_ws)
{
    int idx = blockIdx.x * 256 + threadIdx.x;
    int n = idx & 15;
    int d = (idx >> 4) % DD;
    int grp = (idx >> 4) / DD % NGRP;
    int b = idx / (NS * DD * NGRP);
    float Av = -__expf(A_log[d * NS + n]);
    float h = Hgrp[((size_t)(b * NGRP + grp) * DD + d) * NS + n];
    #pragma unroll
    for (int j = 0; j < GSZ; j++) {
        int g = grp * GSZ + j;
        size_t cb = (size_t)(b * NG + g) * DD + d;
        H_ws[cb * NS + n] = h;
        float a = __expf(sd_ws[cb] * Av);
        h = fmaf(a, h, S_ws[cb * NS + n]);
    }
}

// ---------------------------------------------------------------------------
__global__ __launch_bounds__(64) void scan_pass2(
    const _Float16* __restrict__ uh, const _Float16* __restrict__ ul,
    const float* __restrict__ dtb, const float* __restrict__ Bb,
    const float* __restrict__ Cb, const float* __restrict__ A_log,
    const float* __restrict__ dtw, const float* __restrict__ dtbias,
    const float* __restrict__ H_ws,
    const _Float16* __restrict__ zsH, const _Float16* __restrict__ zsL,
    const float* __restrict__ Dvec,
    _Float16* __restrict__ yh, _Float16* __restrict__ yl)
{
    int g = blockIdx.x, dblk = blockIdx.y, b = blockIdx.z;
    int d = dblk * 64 + threadIdx.x;
    size_t tbase = (size_t)b * LL + g * LC;
    float Av[NS];
    #pragma unroll
    for (int n = 0; n < NS; n++) Av[n] = -__expf(A_log[d * NS + n]);
    float w6[RR];
    #pragma unroll
    for (int r = 0; r < RR; r++) w6[r] = dtw[d * RR + r];
    float b2 = 2.f * dtbias[d];
    float h[NS];
    size_t o = ((size_t)(b * NG + g) * DD + d) * NS;
    #pragma unroll
    for (int q = 0; q < 4; q++) {
        f32x4 hv = *(const f32x4*)(H_ws + o + q * 4);
        #pragma unroll
        for (int e = 0; e < 4; e++) h[q * 4 + e] = hv[e];
    }
    float Dv = Dvec[d];
    const _Float16* uhp = uh + tbase * DD + d;
    const _Float16* ulp = ul + tbase * DD + d;
    const _Float16* zhp = zsH + tbase * DD + d;
    const _Float16* zlp = zsL + tbase * DD + d;
    _Float16* yhp = yh + tbase * DD + d;
    _Float16* ylp = yl + tbase * DD + d;
    #pragma unroll 2
    for (int t = 0; t < LC; t++) {
        f32x4 d0 = *(const f32x4*)&dtb[(tbase + t) * 8];
        f32x4 d1 = *(const f32x4*)&dtb[(tbase + t) * 8 + 4];
        float s = b2;
        s = fmaf(d0[0], w6[0], s); s = fmaf(d0[1], w6[1], s);
        s = fmaf(d0[2], w6[2], s); s = fmaf(d0[3], w6[3], s);
        s = fmaf(d1[0], w6[4], s); s = fmaf(d1[1], w6[5], s);
        float dlt = softplusf(s);
        float uu = ((float)uhp[(size_t)t * DD] + (float)ulp[(size_t)t * DD]) * (1.f / SA);
        float du = dlt * uu;
        f32x4 Bv[4], Cv[4];
        #pragma unroll
        for (int q = 0; q < 4; q++) {
            Bv[q] = *(const f32x4*)&Bb[(tbase + t) * 16 + q * 4];
            Cv[q] = *(const f32x4*)&Cb[(tbase + t) * 16 + q * 4];
        }
        float yv = 0.f;
        #pragma unroll
        for (int n = 0; n < NS; n++) {
            float a = __expf(dlt * Av[n]);
            h[n] = fmaf(a, h[n], du * Bv[n >> 2][n & 3]);
            yv = fmaf(h[n], Cv[n >> 2][n & 3], yv);
        }
        float zv = (float)zhp[(size_t)t * DD] + (float)zlp[(size_t)t * DD];
        float y = (yv + uu * Dv) * zv * SY;
        _Float16 hh = (_Float16)y;
        yhp[(size_t)t * DD] = hh;
        ylp[(size_t)t * DD] = (_Float16)(y - (float)hh);
    }
}

// ---------------------------------------------------------------------------
extern "C" void kernel_launch(void* const* d_in, const int* in_sizes, int n_in,
                              void* d_out, int out_size, void* d_ws, size_t ws_size,
                              hipStream_t stream)
{
    (void)in_sizes; (void)n_in; (void)out_size; (void)ws_size;
    const float* x        = (const float*)d_in[0];
    const float* K        = (const float*)d_in[1];
    const float* Q        = (const float*)d_in[2];
    const float* in_projw = (const float*)d_in[3];
    const float* conv_w   = (const float*)d_in[4];
    const float* conv_b   = (const float*)d_in[5];
    const float* k_ln_g   = (const float*)d_in[6];
    const float* k_ln_b   = (const float*)d_in[7];
    const float* k_w      = (const float*)d_in[8];
    const float* k_b      = (const float*)d_in[9];
    const float* q_ln_g   = (const float*)d_in[10];
    const float* q_ln_b   = (const float*)d_in[11];
    const float* q_w      = (const float*)d_in[12];
    const float* q_b      = (const float*)d_in[13];
    const float* dtbc_w   = (const float*)d_in[14];
    const float* dt_w     = (const float*)d_in[15];
    const float* dt_b     = (const float*)d_in[16];
    const float* gate_w   = (const float*)d_in[17];
    const float* gate_b   = (const float*)d_in[18];
    const float* A_log    = (const float*)d_in[19];
    const float* Dvec     = (const float*)d_in[20];
    const float* out_w    = (const float*)d_in[21];
    float* out = (float*)d_out;

    const size_t S0 = (size_t)MTOK * DD;
    char* base = (char*)d_ws;
    size_t off = 0;
    auto alloc = [&](size_t bytes) {
        char* p = base + off;
        off += (bytes + 255) & ~(size_t)255;
        return p;
    };
    float*     xin   = (float*)alloc(S0 * 4);
    _Float16*  zsH   = (_Float16*)alloc(S0 * 2);
    _Float16*  zsL   = (_Float16*)alloc(S0 * 2);
    _Float16*  uH    = (_Float16*)alloc(S0 * 2);
    _Float16*  uL    = (_Float16*)alloc(S0 * 2);
    _Float16*  KpH   = (_Float16*)alloc(S0 * 2);         // reused as yH
    _Float16*  KpL   = (_Float16*)alloc(S0 * 2);         // reused as yL
    _Float16*  QpH   = (_Float16*)alloc(S0 * 2);
    _Float16*  QpL   = (_Float16*)alloc(S0 * 2);
    float*     dtbB  = (float*)alloc((size_t)MTOK * 8 * 4);
    float*     Bb    = (float*)alloc((size_t)MTOK * 16 * 4);
    float*     Cb    = (float*)alloc((size_t)MTOK * 16 * 4);
    float*     gwK   = (float*)alloc(DD * CD * 4);
    float*     gwQ   = (float*)alloc(DD * CD * 4);
    float*     wsumK = (float*)alloc(DD * 4);
    float*     biasK = (float*)alloc(DD * 4);
    float*     wsumQ = (float*)alloc(DD * 4);
    float*     biasQ = (float*)alloc(DD * 4);
    _Float16*  ipWh  = (_Float16*)alloc(DD * CD * 2);
    _Float16*  ipWl  = (_Float16*)alloc(DD * CD * 2);
    _Float16*  kWh   = (_Float16*)alloc(DD * CD * 2);
    _Float16*  kWl   = (_Float16*)alloc(DD * CD * 2);
    _Float16*  qWh   = (_Float16*)alloc(DD * CD * 2);
    _Float16*  qWl   = (_Float16*)alloc(DD * CD * 2);
    _Float16*  dbWh  = (_Float16*)alloc(48 * 384 * 2);
    _Float16*  dbWl  = (_Float16*)alloc(48 * 384 * 2);
    _Float16*  gWh   = (_Float16*)alloc(DD * 384 * 2);
    _Float16*  gWl   = (_Float16*)alloc(DD * 384 * 2);
    _Float16*  oWh   = (_Float16*)alloc(96 * DD * 2);
    _Float16*  oWl   = (_Float16*)alloc(96 * DD * 2);
    float*     sd_ws = (float*)alloc((size_t)BZ * NG * DD * 4);
    float*     S_ws  = (float*)alloc((size_t)BZ * NG * DD * NS * 4);
    float*     H_ws  = (float*)alloc((size_t)BZ * NG * DD * NS * 4);
    float*     Sg    = (float*)alloc((size_t)BZ * NGRP * DD * NS * 4);
    float*     sdg   = (float*)alloc((size_t)BZ * NGRP * DD * 4);
    float*     Hgrp  = (float*)alloc((size_t)BZ * NGRP * DD * NS * 4);
    _Float16* yH = KpH;
    _Float16* yL = KpL;

    prep_kernel<<<dim3(DD, 2), 96, 0, stream>>>(k_ln_g, k_ln_b, k_w, k_b,
        q_ln_g, q_ln_b, q_w, q_b, gwK, wsumK, biasK, gwQ, wsumQ, biasQ);
    {
        const int total = 18432 * 5 + 73728;
        split_all_kernel<<<(total + 255) / 256, 256, 0, stream>>>(
            in_projw, gwK, gwQ, dtbc_w, gate_w, out_w,
            ipWh, ipWl, kWh, kWl, qWh, qWl, dbWh, dbWl, gWh, gWl, oWh, oWl);
    }

    mfma_projCH3<<<dim3(LL / 64, BZ, 3), 256, 0, stream>>>(
        x, K, Q, ipWh, ipWl, kWh, kWl, qWh, qWl,
        wsumK, biasK, wsumQ, biasQ, xin, KpH, KpL, QpH, QpL);
    conv_kernel<<<(MTOK / 4) * (DD / 4) / 256, 256, 0, stream>>>(xin, conv_w, conv_b, uH, uL);
    gemm_zx<<<ZBLK + MTOK / 128, 256, 0, stream>>>(
        uH, uL, QpH, QpL, KpH, KpL, gWh, gWl, dbWh, dbWl, gate_b,
        zsH, zsL, dtbB, Bb, Cb);
    scan_pass1<<<dim3(NG, DD / 64, BZ), 64, 0, stream>>>(
        uH, uL, dtbB, Bb, A_log, dt_w, dt_b, sd_ws, S_ws);
    combine_a<<<(BZ * NGRP * DD * NS) / 256, 256, 0, stream>>>(sd_ws, S_ws, A_log, Sg, sdg);
    combine_b<<<(BZ * DD * NS) / 256, 256, 0, stream>>>(Sg, sdg, A_log, Hgrp);
    combine_c<<<(BZ * NGRP * DD * NS) / 256, 256, 0, stream>>>(sd_ws, S_ws, Hgrp, A_log, H_ws);
    scan_pass2<<<dim3(NG, DD / 64, BZ), 64, 0, stream>>>(
        uH, uL, dtbB, Bb, Cb, A_log, dt_w, dt_b, H_ws, zsH, zsL, Dvec, yH, yL);
    gemm_out<<<MTOK / 64, 256, 0, stream>>>(yH, yL, oWh, oWl, out);
}

// Round 9
// 372.213 us; speedup vs baseline: 1.1686x; 1.0388x over previous
//
#include <hip/hip_runtime.h>
#include <cstdint>
#include <cstddef>

#define BZ 4
#define CD 96
#define LL 9216
#define DD 192
#define NS 16
#define RR 6
#define LC 32
#define NG 288
#define NGRP 16
#define GSZ 18
#define MTOK (BZ * LL)

#define SA 256.0f
#define SW 1024.0f
#define SY 16.0f

typedef _Float16 f16x8 __attribute__((ext_vector_type(8)));
typedef _Float16 f16x4 __attribute__((ext_vector_type(4)));
typedef float f32x4 __attribute__((ext_vector_type(4)));

__device__ __forceinline__ float siluf(float x) {
    return x / (1.f + __expf(-x));
}
__device__ __forceinline__ float softplusf(float x) {
    return fmaxf(x, 0.f) + log1pf(__expf(-fabsf(x)));
}

// ---------------------------------------------------------------------------
__global__ void prep_kernel(const float* kg, const float* kb, const float* kw, const float* kbias,
                            const float* qg, const float* qb, const float* qw, const float* qbias,
                            float* gwK, float* wsumK, float* biasK,
                            float* gwQ, float* wsumQ, float* biasQ) {
    int d = blockIdx.x;
    const float* g  = blockIdx.y ? qg : kg;
    const float* lb = blockIdx.y ? qb : kb;
    const float* w  = blockIdx.y ? qw : kw;
    const float* b2 = blockIdx.y ? qbias : kbias;
    float* gw = blockIdx.y ? gwQ : gwK;
    float* wsv = blockIdx.y ? wsumQ : wsumK;
    float* bv = blockIdx.y ? biasQ : biasK;
    int c = threadIdx.x;
    __shared__ float s1[96], s2[96];
    float wv = w[d * 96 + c];
    float gv = g[c] * wv;
    gw[d * 96 + c] = gv;
    s1[c] = gv;
    s2[c] = lb[c] * wv;
    __syncthreads();
    if (c < 32) { s1[c] += s1[c + 64]; s2[c] += s2[c + 64]; }
    __syncthreads();
    for (int s = 32; s >= 1; s >>= 1) {
        if (c < s) { s1[c] += s1[c + s]; s2[c] += s2[c + s]; }
        __syncthreads();
    }
    if (c == 0) { wsv[d] = s1[0]; bv[d] = b2[d] + s2[0]; }
}

// ---------------------------------------------------------------------------
__global__ __launch_bounds__(256) void split_all_kernel(
    const float* __restrict__ s0, const float* __restrict__ s1, const float* __restrict__ s2,
    const float* __restrict__ s3, const float* __restrict__ s4, const float* __restrict__ s5,
    _Float16* __restrict__ d0h, _Float16* __restrict__ d0l,
    _Float16* __restrict__ d1h, _Float16* __restrict__ d1l,
    _Float16* __restrict__ d2h, _Float16* __restrict__ d2l,
    _Float16* __restrict__ d3h, _Float16* __restrict__ d3l,
    _Float16* __restrict__ d4h, _Float16* __restrict__ d4l,
    _Float16* __restrict__ d5h, _Float16* __restrict__ d5l)
{
    int idx = blockIdx.x * 256 + threadIdx.x;
    const int C0 = 18432, C1 = 18432, C2 = 18432, C3 = 18432, C4 = 73728, C5 = 18432;
    const float* src; _Float16* dh; _Float16* dl; int i; bool pad = false;
    if (idx < C0) { src = s0; dh = d0h; dl = d0l; i = idx; }
    else if (idx < C0 + C1) { src = s1; dh = d1h; dl = d1l; i = idx - C0; }
    else if (idx < C0 + C1 + C2) { src = s2; dh = d2h; dl = d2l; i = idx - C0 - C1; }
    else if (idx < C0 + C1 + C2 + C3) {
        src = s3; dh = d3h; dl = d3l; i = idx - C0 - C1 - C2;
        pad = (i / 384) >= 38;   // dtbc_w: 38 real rows padded to 48
    }
    else if (idx < C0 + C1 + C2 + C3 + C4) { src = s4; dh = d4h; dl = d4l; i = idx - C0 - C1 - C2 - C3; }
    else if (idx < C0 + C1 + C2 + C3 + C4 + C5) { src = s5; dh = d5h; dl = d5l; i = idx - C0 - C1 - C2 - C3 - C4; }
    else return;
    float v = pad ? 0.f : src[i] * SW;
    _Float16 h = (_Float16)v;
    dh[i] = h;
    dl[i] = (_Float16)(v - (float)h);
}

// ---------------------------------------------------------------------------
// Merged MFMA projection (x / K / Q by blockIdx.z), K=96, N=192.
__global__ __launch_bounds__(256) void mfma_projCH3(
    const float* __restrict__ xA, const float* __restrict__ KA, const float* __restrict__ QA,
    const _Float16* __restrict__ ipWh, const _Float16* __restrict__ ipWl,
    const _Float16* __restrict__ kWh, const _Float16* __restrict__ kWl,
    const _Float16* __restrict__ qWh, const _Float16* __restrict__ qWl,
    const float* __restrict__ wsumK, const float* __restrict__ biasK,
    const float* __restrict__ wsumQ, const float* __restrict__ biasQ,
    float* __restrict__ xin,
    _Float16* __restrict__ KpH, _Float16* __restrict__ KpL,
    _Float16* __restrict__ QpH, _Float16* __restrict__ QpL)
{
    int which = blockIdx.z;
    const float* A = which == 0 ? xA : (which == 1 ? KA : QA);
    const _Float16* Wh = which == 0 ? ipWh : (which == 1 ? kWh : qWh);
    const _Float16* Wl = which == 0 ? ipWl : (which == 1 ? kWl : qWl);
    const float* wsum = which == 1 ? wsumK : wsumQ;
    const float* biasv = which == 1 ? biasK : biasQ;
    _Float16* outH = which == 1 ? KpH : QpH;
    _Float16* outL = which == 1 ? KpL : QpL;
    bool LN = which != 0;

    int b = blockIdx.y;
    int l0 = blockIdx.x * 64;
    int tid = threadIdx.x;
    int lane = tid & 63, w = tid >> 6;

    __shared__ __align__(16) _Float16 Ah[64 * 104];
    __shared__ __align__(16) _Float16 Al[64 * 104];
    __shared__ float sm[64], siv[64];
    __shared__ float red1[256], red2[256];

    {
        float s = 0.f, ss = 0.f;
        #pragma unroll 4
        for (int i = tid; i < 96 * 64; i += 256) {
            int c = i >> 6, l = i & 63;
            float a = A[((size_t)b * CD + c) * LL + l0 + l];
            float v = a * SA;
            _Float16 h = (_Float16)v;
            Ah[l * 104 + c] = h;
            Al[l * 104 + c] = (_Float16)(v - (float)h);
            s += a; ss += a * a;
        }
        if (LN) { red1[tid] = s; red2[tid] = ss; }
    }
    __syncthreads();
    if (LN && tid < 64) {
        float s4 = red1[tid] + red1[tid + 64] + red1[tid + 128] + red1[tid + 192];
        float q4 = red2[tid] + red2[tid + 64] + red2[tid + 128] + red2[tid + 192];
        float m = s4 / 96.f;
        sm[tid] = m;
        siv[tid] = rsqrtf(fmaxf(q4 / 96.f - m * m, 0.f) + 1e-5f);
    }
    if (LN) __syncthreads();

    int col = lane & 15, quad = lane >> 4;
    int n0 = w * 48;
    f32x4 zv4 = {0.f, 0.f, 0.f, 0.f};
    f32x4 acc[4][3];
    #pragma unroll
    for (int mi = 0; mi < 4; mi++)
        #pragma unroll
        for (int ni = 0; ni < 3; ni++) acc[mi][ni] = zv4;
    for (int c0 = 0; c0 < 96; c0 += 32) {
        f16x8 afh[4], afl[4], bfh[3], bfl[3];
        #pragma unroll
        for (int mi = 0; mi < 4; mi++) {
            int off = (16 * mi + col) * 104 + c0 + quad * 8;
            afh[mi] = *(const f16x8*)&Ah[off];
            afl[mi] = *(const f16x8*)&Al[off];
        }
        #pragma unroll
        for (int ni = 0; ni < 3; ni++) {
            size_t off = (size_t)(n0 + ni * 16 + col) * 96 + c0 + quad * 8;
            bfh[ni] = *(const f16x8*)&Wh[off];
            bfl[ni] = *(const f16x8*)&Wl[off];
        }
        #pragma unroll
        for (int mi = 0; mi < 4; mi++)
            #pragma unroll
            for (int ni = 0; ni < 3; ni++) {
                acc[mi][ni] = __builtin_amdgcn_mfma_f32_16x16x32_f16(afh[mi], bfl[ni], acc[mi][ni], 0, 0, 0);
                acc[mi][ni] = __builtin_amdgcn_mfma_f32_16x16x32_f16(afl[mi], bfh[ni], acc[mi][ni], 0, 0, 0);
                acc[mi][ni] = __builtin_amdgcn_mfma_f32_16x16x32_f16(afh[mi], bfh[ni], acc[mi][ni], 0, 0, 0);
            }
    }
    const float isc = 1.f / (SA * SW);
    if (LN) {
        #pragma unroll
        for (int ni = 0; ni < 3; ni++) {
            int d = n0 + ni * 16 + col;
            float wsv = wsum[d];
            float bvv = biasv[d];
            #pragma unroll
            for (int mi = 0; mi < 4; mi++)
                #pragma unroll
                for (int r = 0; r < 4; r++) {
                    int tl = mi * 16 + quad * 4 + r;
                    float v = acc[mi][ni][r] * isc;
                    size_t t = (size_t)b * LL + l0 + tl;
                    v = (v - sm[tl] * wsv) * siv[tl] + bvv;
                    v = siluf(v) * SA;
                    _Float16 h = (_Float16)v;
                    outH[t * DD + d] = h;
                    outL[t * DD + d] = (_Float16)(v - (float)h);
                }
        }
    } else {
        #pragma unroll
        for (int ni = 0; ni < 3; ni++) {
            int d = n0 + ni * 16 + col;
            #pragma unroll
            for (int mi = 0; mi < 4; mi++)
                #pragma unroll
                for (int r = 0; r < 4; r++) {
                    int tl = mi * 16 + quad * 4 + r;
                    size_t t = (size_t)b * LL + l0 + tl;
                    xin[t * DD + d] = acc[mi][ni][r] * isc;
                }
        }
    }
}

// ---------------------------------------------------------------------------
__global__ __launch_bounds__(256) void conv_kernel(const float* __restrict__ xin,
        const float* __restrict__ cw, const float* __restrict__ cb,
        _Float16* __restrict__ uh, _Float16* __restrict__ ul)
{
    int gid = blockIdx.x * 256 + threadIdx.x;
    int dg = gid % (DD / 4);
    int tg = gid / (DD / 4);
    int b = tg / (LL / 4);
    int l0 = (tg % (LL / 4)) * 4;
    size_t rowbase = ((size_t)b * LL + l0) * DD + dg * 4;
    f32x4 r[7];
    #pragma unroll
    for (int j = 0; j < 7; j++) {
        int l = l0 - 3 + j;
        f32x4 z4 = {0.f, 0.f, 0.f, 0.f};
        r[j] = (l >= 0) ? *(const f32x4*)&xin[rowbase + (size_t)(j - 3) * DD] : z4;
    }
    float cwv[4][4], cb4[4];
    #pragma unroll
    for (int e = 0; e < 4; e++) {
        cb4[e] = cb[dg * 4 + e];
        #pragma unroll
        for (int j = 0; j < 4; j++) cwv[e][j] = cw[(dg * 4 + e) * 4 + j];
    }
    #pragma unroll
    for (int tt = 0; tt < 4; tt++) {
        f16x4 oh, ol;
        #pragma unroll
        for (int e = 0; e < 4; e++) {
            float s = cb4[e];
            #pragma unroll
            for (int j = 0; j < 4; j++) s = fmaf(cwv[e][j], r[tt + j][e], s);
            float u = siluf(s) * SA;
            _Float16 h = (_Float16)u;
            oh[e] = h;
            ol[e] = (_Float16)(u - (float)h);
        }
        *(f16x4*)&uh[rowbase + (size_t)tt * DD] = oh;
        *(f16x4*)&ul[rowbase + (size_t)tt * DD] = ol;
    }
}

// ---------------------------------------------------------------------------
// LDS-tiled, register-prefetch-pipelined fused z-GEMM + xdbl-GEMM.
// K=384, BK=32, 12 iters. Blocks = 64 tokens.
// z (blockIdx < MTOK/64): N=192, wave = 32tok x 96N.
// xdbl: N=48, wave = 16tok x 48N.
// Pipeline: commit regs->LDS, issue next iter's global loads, barrier, compute.
__global__ __launch_bounds__(256) void gemm_zx(
    const _Float16* __restrict__ uH, const _Float16* __restrict__ uL,
    const _Float16* __restrict__ QpH, const _Float16* __restrict__ QpL,
    const _Float16* __restrict__ KpH, const _Float16* __restrict__ KpL,
    const _Float16* __restrict__ gWh, const _Float16* __restrict__ gWl,
    const _Float16* __restrict__ dbWh, const _Float16* __restrict__ dbWl,
    const float* __restrict__ gate_b,
    _Float16* __restrict__ zsH, _Float16* __restrict__ zsL,
    float* __restrict__ dtbp, float* __restrict__ Bbp, float* __restrict__ Cbp)
{
    __shared__ __align__(16) _Float16 Ah_s[64 * 40];
    __shared__ __align__(16) _Float16 Al_s[64 * 40];
    __shared__ __align__(16) _Float16 Wh_s[192 * 40];
    __shared__ __align__(16) _Float16 Wl_s[192 * 40];
    int tid = threadIdx.x;
    int lane = tid & 63, w = tid >> 6;
    int col = lane & 15, quad = lane >> 4;
    const int ZB = MTOK / 64;   // 576
    bool isz = (int)blockIdx.x < ZB;
    int t0 = (isz ? blockIdx.x : blockIdx.x - ZB) * 64;
    const _Float16* A1h = isz ? QpH : KpH;
    const _Float16* A1l = isz ? QpL : KpL;
    const _Float16* Bh  = isz ? gWh : dbWh;
    const _Float16* Bl  = isz ? gWl : dbWl;
    const float osc = 1.f / (SA * SW);

    // A staging: 512 chunks of 16B (64 rows x 4 x 2 planes), 2 per thread.
    int cA0 = tid, cA1 = tid + 256;
    int rA0 = (cA0 >> 2) & 63, pA0 = cA0 & 3, plA0 = cA0 >> 8;
    int rA1 = (cA1 >> 2) & 63, pA1 = cA1 & 3, plA1 = cA1 >> 8;

    if (isz) {
        int m0 = (w & 1) * 32;
        int n0 = (w >> 1) * 96;
        // W staging: 1536 chunks (192 rows x 4 x 2 planes), 6 per thread.
        f32x4 zv4 = {0.f, 0.f, 0.f, 0.f};
        f32x4 acc[2][6];
        #pragma unroll
        for (int mi = 0; mi < 2; mi++)
            #pragma unroll
            for (int ni = 0; ni < 6; ni++) acc[mi][ni] = zv4;
        f16x8 pfA[2], pfW[6];
        // prologue: issue k0 = 0
        pfA[0] = *(const f16x8*)&(plA0 ? uL : uH)[(size_t)(t0 + rA0) * DD + pA0 * 8];
        pfA[1] = *(const f16x8*)&(plA1 ? uL : uH)[(size_t)(t0 + rA1) * DD + pA1 * 8];
        #pragma unroll
        for (int j = 0; j < 6; j++) {
            int c = tid + 256 * j;
            int pl = c >= 768; int cc = pl ? c - 768 : c;
            int r = cc >> 2, p = cc & 3;
            pfW[j] = *(const f16x8*)&(pl ? Bl : Bh)[(size_t)r * 384 + p * 8];
        }
        for (int k0 = 0; k0 < 384; k0 += 32) {
            __syncthreads();
            // commit current regs -> LDS
            *(f16x8*)&(plA0 ? Al_s : Ah_s)[rA0 * 40 + pA0 * 8] = pfA[0];
            *(f16x8*)&(plA1 ? Al_s : Ah_s)[rA1 * 40 + pA1 * 8] = pfA[1];
            #pragma unroll
            for (int j = 0; j < 6; j++) {
                int c = tid + 256 * j;
                int pl = c >= 768; int cc = pl ? c - 768 : c;
                int r = cc >> 2, p = cc & 3;
                *(f16x8*)&(pl ? Wl_s : Wh_s)[r * 40 + p * 8] = pfW[j];
            }
            // issue next iter's loads (latency overlaps compute below)
            if (k0 + 32 < 384) {
                int kn = k0 + 32;
                const _Float16* Ash = (kn >= 192) ? A1h : uH;
                const _Float16* Asl = (kn >= 192) ? A1l : uL;
                int kc = (kn >= 192) ? kn - 192 : kn;
                pfA[0] = *(const f16x8*)&(plA0 ? Asl : Ash)[(size_t)(t0 + rA0) * DD + kc + pA0 * 8];
                pfA[1] = *(const f16x8*)&(plA1 ? Asl : Ash)[(size_t)(t0 + rA1) * DD + kc + pA1 * 8];
                #pragma unroll
                for (int j = 0; j < 6; j++) {
                    int c = tid + 256 * j;
                    int pl = c >= 768; int cc = pl ? c - 768 : c;
                    int r = cc >> 2, p = cc & 3;
                    pfW[j] = *(const f16x8*)&(pl ? Bl : Bh)[(size_t)r * 384 + kn + p * 8];
                }
            }
            __syncthreads();
            f16x8 afh[2], afl[2];
            #pragma unroll
            for (int mi = 0; mi < 2; mi++) {
                int r = m0 + mi * 16 + col;
                afh[mi] = *(const f16x8*)&Ah_s[r * 40 + quad * 8];
                afl[mi] = *(const f16x8*)&Al_s[r * 40 + quad * 8];
            }
            #pragma unroll
            for (int ni = 0; ni < 6; ni++) {
                int r = n0 + ni * 16 + col;
                f16x8 bfh = *(const f16x8*)&Wh_s[r * 40 + quad * 8];
                f16x8 bfl = *(const f16x8*)&Wl_s[r * 40 + quad * 8];
                #pragma unroll
                for (int mi = 0; mi < 2; mi++) {
                    acc[mi][ni] = __builtin_amdgcn_mfma_f32_16x16x32_f16(afh[mi], bfl, acc[mi][ni], 0, 0, 0);
                    acc[mi][ni] = __builtin_amdgcn_mfma_f32_16x16x32_f16(afl[mi], bfh, acc[mi][ni], 0, 0, 0);
                    acc[mi][ni] = __builtin_amdgcn_mfma_f32_16x16x32_f16(afh[mi], bfh, acc[mi][ni], 0, 0, 0);
                }
            }
        }
        #pragma unroll
        for (int ni = 0; ni < 6; ni++) {
            int d = n0 + ni * 16 + col;
            float bv = gate_b[d];
            #pragma unroll
            for (int mi = 0; mi < 2; mi++)
                #pragma unroll
                for (int r = 0; r < 4; r++) {
                    size_t t = t0 + m0 + mi * 16 + quad * 4 + r;
                    float z = siluf(acc[mi][ni][r] * osc + bv);
                    _Float16 h = (_Float16)z;
                    zsH[t * DD + d] = h;
                    zsL[t * DD + d] = (_Float16)(z - (float)h);
                }
        }
    } else {
        int m0 = w * 16;
        // W staging: 384 chunks (48 rows x 4 x 2 planes); threads 0..383 via 2 slots.
        int cW0 = tid, cW1 = tid + 256;
        bool hW1 = cW1 < 384;
        int plW0 = cW0 >= 192; int ccW0 = plW0 ? cW0 - 192 : cW0;
        int rW0 = ccW0 >> 2, pW0 = ccW0 & 3;
        int ccW1 = cW1 - 192;  // cW1 in [256,384) -> always lo plane
        int rW1 = ccW1 >> 2, pW1 = ccW1 & 3;
        f32x4 zv4 = {0.f, 0.f, 0.f, 0.f};
        f32x4 acc[1][3];
        #pragma unroll
        for (int ni = 0; ni < 3; ni++) acc[0][ni] = zv4;
        f16x8 pfA[2], pfW0, pfW1;
        pfA[0] = *(const f16x8*)&(plA0 ? uL : uH)[(size_t)(t0 + rA0) * DD + pA0 * 8];
        pfA[1] = *(const f16x8*)&(plA1 ? uL : uH)[(size_t)(t0 + rA1) * DD + pA1 * 8];
        pfW0 = *(const f16x8*)&(plW0 ? Bl : Bh)[(size_t)rW0 * 384 + pW0 * 8];
        if (hW1) pfW1 = *(const f16x8*)&Bl[(size_t)rW1 * 384 + pW1 * 8];
        for (int k0 = 0; k0 < 384; k0 += 32) {
            __syncthreads();
            *(f16x8*)&(plA0 ? Al_s : Ah_s)[rA0 * 40 + pA0 * 8] = pfA[0];
            *(f16x8*)&(plA1 ? Al_s : Ah_s)[rA1 * 40 + pA1 * 8] = pfA[1];
            *(f16x8*)&(plW0 ? Wl_s : Wh_s)[rW0 * 40 + pW0 * 8] = pfW0;
            if (hW1) *(f16x8*)&Wl_s[rW1 * 40 + pW1 * 8] = pfW1;
            if (k0 + 32 < 384) {
                int kn = k0 + 32;
                const _Float16* Ash = (kn >= 192) ? A1h : uH;
                const _Float16* Asl = (kn >= 192) ? A1l : uL;
                int kc = (kn >= 192) ? kn - 192 : kn;
                pfA[0] = *(const f16x8*)&(plA0 ? Asl : Ash)[(size_t)(t0 + rA0) * DD + kc + pA0 * 8];
                pfA[1] = *(const f16x8*)&(plA1 ? Asl : Ash)[(size_t)(t0 + rA1) * DD + kc + pA1 * 8];
                pfW0 = *(const f16x8*)&(plW0 ? Bl : Bh)[(size_t)rW0 * 384 + kn + pW0 * 8];
                if (hW1) pfW1 = *(const f16x8*)&Bl[(size_t)rW1 * 384 + kn + pW1 * 8];
            }
            __syncthreads();
            f16x8 afh, afl;
            {
                int r = m0 + col;
                afh = *(const f16x8*)&Ah_s[r * 40 + quad * 8];
                afl = *(const f16x8*)&Al_s[r * 40 + quad * 8];
            }
            #pragma unroll
            for (int ni = 0; ni < 3; ni++) {
                int r = ni * 16 + col;
                f16x8 bfh = *(const f16x8*)&Wh_s[r * 40 + quad * 8];
                f16x8 bfl = *(const f16x8*)&Wl_s[r * 40 + quad * 8];
                acc[0][ni] = __builtin_amdgcn_mfma_f32_16x16x32_f16(afh, bfl, acc[0][ni], 0, 0, 0);
                acc[0][ni] = __builtin_amdgcn_mfma_f32_16x16x32_f16(afl, bfh, acc[0][ni], 0, 0, 0);
                acc[0][ni] = __builtin_amdgcn_mfma_f32_16x16x32_f16(afh, bfh, acc[0][ni], 0, 0, 0);
            }
        }
        #pragma unroll
        for (int ni = 0; ni < 3; ni++) {
            int d = ni * 16 + col;
            #pragma unroll
            for (int r = 0; r < 4; r++) {
                size_t t = t0 + m0 + quad * 4 + r;
                float v = acc[0][ni][r] * osc;
                if (d < 6)       dtbp[t * 8 + d] = v;
                else if (d < 22) Bbp[t * 16 + (d - 6)] = v;
                else if (d < 38) Cbp[t * 16 + (d - 22)] = v;
                else if (d < 40) dtbp[t * 8 + (d - 32)] = 0.f;
            }
        }
    }
}

// ---------------------------------------------------------------------------
// Pipelined 32tok x 48n wave-tile GEMM core (direct-from-global; used by out).
__device__ __forceinline__ void mfma_set3(
    const f16x8 (&ah)[2], const f16x8 (&al)[2],
    const f16x8 (&bh)[3], const f16x8 (&bl)[3], f32x4 (&acc)[2][3])
{
    #pragma unroll
    for (int mi = 0; mi < 2; mi++)
        #pragma unroll
        for (int ni = 0; ni < 3; ni++) {
            acc[mi][ni] = __builtin_amdgcn_mfma_f32_16x16x32_f16(ah[mi], bl[ni], acc[mi][ni], 0, 0, 0);
            acc[mi][ni] = __builtin_amdgcn_mfma_f32_16x16x32_f16(al[mi], bh[ni], acc[mi][ni], 0, 0, 0);
            acc[mi][ni] = __builtin_amdgcn_mfma_f32_16x16x32_f16(ah[mi], bh[ni], acc[mi][ni], 0, 0, 0);
        }
}

template<int KD>
__device__ __forceinline__ void gemm_core32(
    const _Float16* __restrict__ A0h, const _Float16* __restrict__ A0l,
    const _Float16* __restrict__ Wh, const _Float16* __restrict__ Wl,
    int t0, int n0, int col, int quad, f32x4 (&acc)[2][3])
{
    f16x8 ah[2][2], al[2][2], bh[2][3], bl[2][3];
    auto loadA = [&](int k0, int s) {
        #pragma unroll
        for (int mi = 0; mi < 2; mi++) {
            size_t off = (size_t)(t0 + mi * 16 + col) * DD + k0 + quad * 8;
            ah[s][mi] = *(const f16x8*)&A0h[off];
            al[s][mi] = *(const f16x8*)&A0l[off];
        }
    };
    auto loadB = [&](int k0, int s) {
        #pragma unroll
        for (int ni = 0; ni < 3; ni++) {
            size_t off = (size_t)(n0 + ni * 16 + col) * KD + k0 + quad * 8;
            bh[s][ni] = *(const f16x8*)&Wh[off];
            bl[s][ni] = *(const f16x8*)&Wl[off];
        }
    };
    loadA(0, 0); loadB(0, 0);
    loadA(32, 1); loadB(32, 1);
    #pragma unroll
    for (int k0 = 0; k0 < KD; k0 += 32) {
        int s = (k0 >> 5) & 1;
        mfma_set3(ah[s], al[s], bh[s], bl[s], acc);
        if (k0 + 64 < KD) { loadA(k0 + 64, s); loadB(k0 + 64, s); }
    }
}

// ---------------------------------------------------------------------------
// Final out-projection (K=192): block = 64 tokens x full 96 N.
__global__ __launch_bounds__(256) void gemm_out(
    const _Float16* __restrict__ yH, const _Float16* __restrict__ yL,
    const _Float16* __restrict__ oWh, const _Float16* __restrict__ oWl,
    float* __restrict__ outF)
{
    int tid = threadIdx.x;
    int lane = tid & 63, w = tid >> 6;
    int col = lane & 15, quad = lane >> 4;
    int t0 = blockIdx.x * 64 + (w & 1) * 32;
    int n0 = (w >> 1) * 48;
    f32x4 zv4 = {0.f, 0.f, 0.f, 0.f};
    f32x4 acc[2][3];
    #pragma unroll
    for (int mi = 0; mi < 2; mi++)
        #pragma unroll
        for (int ni = 0; ni < 3; ni++) acc[mi][ni] = zv4;
    gemm_core32<192>(yH, yL, oWh, oWl, t0, n0, col, quad, acc);
    const float osc = 1.f / (SY * SW);
    int bq = t0 / LL;
    int lb = t0 % LL;
    #pragma unroll
    for (int ni = 0; ni < 3; ni++) {
        int d = n0 + ni * 16 + col;
        #pragma unroll
        for (int mi = 0; mi < 2; mi++) {
            f32x4 v;
            #pragma unroll
            for (int r = 0; r < 4; r++) v[r] = acc[mi][ni][r] * osc;
            *(f32x4*)&outF[((size_t)(bq * 96 + d)) * LL + lb + mi * 16 + quad * 4] = v;
        }
    }
}

// ---------------------------------------------------------------------------
// Chunked selective scan. Pass 1 stores per-chunk sd (= sum of delta) and S.
__global__ __launch_bounds__(64) void scan_pass1(
    const _Float16* __restrict__ uh, const _Float16* __restrict__ ul,
    const float* __restrict__ dtb, const float* __restrict__ Bb,
    const float* __restrict__ A_log,
    const float* __restrict__ dtw, const float* __restrict__ dtbias,
    float* __restrict__ sd_ws, float* __restrict__ S_ws)
{
    int g = blockIdx.x, dblk = blockIdx.y, b = blockIdx.z;
    int d = dblk * 64 + threadIdx.x;
    size_t tbase = (size_t)b * LL + g * LC;
    float Av[NS];
    #pragma unroll
    for (int n = 0; n < NS; n++) Av[n] = -__expf(A_log[d * NS + n]);
    float w6[RR];
    #pragma unroll
    for (int r = 0; r < RR; r++) w6[r] = dtw[d * RR + r];
    float b2 = 2.f * dtbias[d];
    float h[NS];
    #pragma unroll
    for (int n = 0; n < NS; n++) h[n] = 0.f;
    float sd = 0.f;
    const _Float16* uhp = uh + tbase * DD + d;
    const _Float16* ulp = ul + tbase * DD + d;
    #pragma unroll 2
    for (int t = 0; t < LC; t++) {
        f32x4 d0 = *(const f32x4*)&dtb[(tbase + t) * 8];
        f32x4 d1 = *(const f32x4*)&dtb[(tbase + t) * 8 + 4];
        float s = b2;
        s = fmaf(d0[0], w6[0], s); s = fmaf(d0[1], w6[1], s);
        s = fmaf(d0[2], w6[2], s); s = fmaf(d0[3], w6[3], s);
        s = fmaf(d1[0], w6[4], s); s = fmaf(d1[1], w6[5], s);
        float dlt = softplusf(s);
        sd += dlt;
        float uu = ((float)uhp[(size_t)t * DD] + (float)ulp[(size_t)t * DD]) * (1.f / SA);
        float du = dlt * uu;
        f32x4 Bv[4];
        #pragma unroll
        for (int q = 0; q < 4; q++) Bv[q] = *(const f32x4*)&Bb[(tbase + t) * 16 + q * 4];
        #pragma unroll
        for (int n = 0; n < NS; n++) {
            float a = __expf(dlt * Av[n]);
            h[n] = fmaf(a, h[n], du * Bv[n >> 2][n & 3]);
        }
    }
    size_t o = ((size_t)(b * NG + g) * DD + d) * NS;
    sd_ws[(size_t)(b * NG + g) * DD + d] = sd;
    #pragma unroll
    for (int q = 0; q < 4; q++) {
        f32x4 sv;
        #pragma unroll
        for (int e = 0; e < 4; e++) sv[e] = h[q * 4 + e];
        *(f32x4*)(S_ws + o + q * 4) = sv;
    }
}

// ---------------------------------------------------------------------------
// 3-level parallel chunk-combine.
__global__ __launch_bounds__(256) void combine_a(
    const float* __restrict__ sd_ws, const float* __restrict__ S_ws,
    const float* __restrict__ A_log,
    float* __restrict__ Sg, float* __restrict__ sdg)
{
    int idx = blockIdx.x * 256 + threadIdx.x;
    int n = idx & 15;
    int d = (idx >> 4) % DD;
    int grp = (idx >> 4) / DD % NGRP;
    int b = idx / (NS * DD * NGRP);
    float Av = -__expf(A_log[d * NS + n]);
    float h = 0.f, sds = 0.f;
    #pragma unroll
    for (int j = 0; j < GSZ; j++) {
        int g = grp * GSZ + j;
        size_t cb = (size_t)(b * NG + g) * DD + d;
        float sd = sd_ws[cb];
        float a = __expf(sd * Av);
        h = fmaf(a, h, S_ws[cb * NS + n]);
        sds += sd;
    }
    size_t o = (size_t)(b * NGRP + grp) * DD + d;
    Sg[o * NS + n] = h;
    if (n == 0) sdg[o] = sds;
}

__global__ __launch_bounds__(256) void combine_b(
    const float* __restrict__ Sg, const float* __restrict__ sdg,
    const float* __restrict__ A_log, float* __restrict__ Hgrp)
{
    int idx = blockIdx.x * 256 + threadIdx.x;
    int n = idx & 15;
    int d = (idx >> 4) % DD;
    int b = idx / (NS * DD);
    float Av = -__expf(A_log[d * NS + n]);
    float h = 0.f;
    #pragma unroll
    for (int grp = 0; grp < NGRP; grp++) {
        size_t o = (size_t)(b * NGRP + grp) * DD + d;
        Hgrp[o * NS + n] = h;
        float a = __expf(sdg[o] * Av);
        h = fmaf(a, h, Sg[o * NS + n]);
    }
}

__global__ __launch_bounds__(256) void combine_c(
    const float* __restrict__ sd_ws, const float* __restrict__ S_ws,
    const float* __restrict__ Hgrp, const float* __restrict__ A_log,
    float* __restrict__ H_ws)
{
    int idx = blockIdx.x * 256 + threadIdx.x;
    int n = idx & 15;
    int d = (idx >> 4) % DD;
    int grp = (idx >> 4) / DD % NGRP;
    int b = idx / (NS * DD * NGRP);
    float Av = -__expf(A_log[d * NS + n]);
    float h = Hgrp[((size_t)(b * NGRP + grp) * DD + d) * NS + n];
    #pragma unroll
    for (int j = 0; j < GSZ; j++) {
        int g = grp * GSZ + j;
        size_t cb = (size_t)(b * NG + g) * DD + d;
        H_ws[cb * NS + n] = h;
        float a = __expf(sd_ws[cb] * Av);
        h = fmaf(a, h, S_ws[cb * NS + n]);
    }
}

// ---------------------------------------------------------------------------
__global__ __launch_bounds__(64) void scan_pass2(
    const _Float16* __restrict__ uh, const _Float16* __restrict__ ul,
    const float* __restrict__ dtb, const float* __restrict__ Bb,
    const float* __restrict__ Cb, const float* __restrict__ A_log,
    const float* __restrict__ dtw, const float* __restrict__ dtbias,
    const float* __restrict__ H_ws,
    const _Float16* __restrict__ zsH, const _Float16* __restrict__ zsL,
    const float* __restrict__ Dvec,
    _Float16* __restrict__ yh, _Float16* __restrict__ yl)
{
    int g = blockIdx.x, dblk = blockIdx.y, b = blockIdx.z;
    int d = dblk * 64 + threadIdx.x;
    size_t tbase = (size_t)b * LL + g * LC;
    float Av[NS];
    #pragma unroll
    for (int n = 0; n < NS; n++) Av[n] = -__expf(A_log[d * NS + n]);
    float w6[RR];
    #pragma unroll
    for (int r = 0; r < RR; r++) w6[r] = dtw[d * RR + r];
    float b2 = 2.f * dtbias[d];
    float h[NS];
    size_t o = ((size_t)(b * NG + g) * DD + d) * NS;
    #pragma unroll
    for (int q = 0; q < 4; q++) {
        f32x4 hv = *(const f32x4*)(H_ws + o + q * 4);
        #pragma unroll
        for (int e = 0; e < 4; e++) h[q * 4 + e] = hv[e];
    }
    float Dv = Dvec[d];
    const _Float16* uhp = uh + tbase * DD + d;
    const _Float16* ulp = ul + tbase * DD + d;
    const _Float16* zhp = zsH + tbase * DD + d;
    const _Float16* zlp = zsL + tbase * DD + d;
    _Float16* yhp = yh + tbase * DD + d;
    _Float16* ylp = yl + tbase * DD + d;
    #pragma unroll 2
    for (int t = 0; t < LC; t++) {
        f32x4 d0 = *(const f32x4*)&dtb[(tbase + t) * 8];
        f32x4 d1 = *(const f32x4*)&dtb[(tbase + t) * 8 + 4];
        float s = b2;
        s = fmaf(d0[0], w6[0], s); s = fmaf(d0[1], w6[1], s);
        s = fmaf(d0[2], w6[2], s); s = fmaf(d0[3], w6[3], s);
        s = fmaf(d1[0], w6[4], s); s = fmaf(d1[1], w6[5], s);
        float dlt = softplusf(s);
        float uu = ((float)uhp[(size_t)t * DD] + (float)ulp[(size_t)t * DD]) * (1.f / SA);
        float du = dlt * uu;
        f32x4 Bv[4], Cv[4];
        #pragma unroll
        for (int q = 0; q < 4; q++) {
            Bv[q] = *(const f32x4*)&Bb[(tbase + t) * 16 + q * 4];
            Cv[q] = *(const f32x4*)&Cb[(tbase + t) * 16 + q * 4];
        }
        float yv = 0.f;
        #pragma unroll
        for (int n = 0; n < NS; n++) {
            float a = __expf(dlt * Av[n]);
            h[n] = fmaf(a, h[n], du * Bv[n >> 2][n & 3]);
            yv = fmaf(h[n], Cv[n >> 2][n & 3], yv);
        }
        float zv = (float)zhp[(size_t)t * DD] + (float)zlp[(size_t)t * DD];
        float y = (yv + uu * Dv) * zv * SY;
        _Float16 hh = (_Float16)y;
        yhp[(size_t)t * DD] = hh;
        ylp[(size_t)t * DD] = (_Float16)(y - (float)hh);
    }
}

// ---------------------------------------------------------------------------
extern "C" void kernel_launch(void* const* d_in, const int* in_sizes, int n_in,
                              void* d_out, int out_size, void* d_ws, size_t ws_size,
                              hipStream_t stream)
{
    (void)in_sizes; (void)n_in; (void)out_size; (void)ws_size;
    const float* x        = (const float*)d_in[0];
    const float* K        = (const float*)d_in[1];
    const float* Q        = (const float*)d_in[2];
    const float* in_projw = (const float*)d_in[3];
    const float* conv_w   = (const float*)d_in[4];
    const float* conv_b   = (const float*)d_in[5];
    const float* k_ln_g   = (const float*)d_in[6];
    const float* k_ln_b   = (const float*)d_in[7];
    const float* k_w      = (const float*)d_in[8];
    const float* k_b      = (const float*)d_in[9];
    const float* q_ln_g   = (const float*)d_in[10];
    const float* q_ln_b   = (const float*)d_in[11];
    const float* q_w      = (const float*)d_in[12];
    const float* q_b      = (const float*)d_in[13];
    const float* dtbc_w   = (const float*)d_in[14];
    const float* dt_w     = (const float*)d_in[15];
    const float* dt_b     = (const float*)d_in[16];
    const float* gate_w   = (const float*)d_in[17];
    const float* gate_b   = (const float*)d_in[18];
    const float* A_log    = (const float*)d_in[19];
    const float* Dvec     = (const float*)d_in[20];
    const float* out_w    = (const float*)d_in[21];
    float* out = (float*)d_out;

    const size_t S0 = (size_t)MTOK * DD;
    char* base = (char*)d_ws;
    size_t off = 0;
    auto alloc = [&](size_t bytes) {
        char* p = base + off;
        off += (bytes + 255) & ~(size_t)255;
        return p;
    };
    float*     xin   = (float*)alloc(S0 * 4);
    _Float16*  zsH   = (_Float16*)alloc(S0 * 2);
    _Float16*  zsL   = (_Float16*)alloc(S0 * 2);
    _Float16*  uH    = (_Float16*)alloc(S0 * 2);
    _Float16*  uL    = (_Float16*)alloc(S0 * 2);
    _Float16*  KpH   = (_Float16*)alloc(S0 * 2);         // reused as yH
    _Float16*  KpL   = (_Float16*)alloc(S0 * 2);         // reused as yL
    _Float16*  QpH   = (_Float16*)alloc(S0 * 2);
    _Float16*  QpL   = (_Float16*)alloc(S0 * 2);
    float*     dtbB  = (float*)alloc((size_t)MTOK * 8 * 4);
    float*     Bb    = (float*)alloc((size_t)MTOK * 16 * 4);
    float*     Cb    = (float*)alloc((size_t)MTOK * 16 * 4);
    float*     gwK   = (float*)alloc(DD * CD * 4);
    float*     gwQ   = (float*)alloc(DD * CD * 4);
    float*     wsumK = (float*)alloc(DD * 4);
    float*     biasK = (float*)alloc(DD * 4);
    float*     wsumQ = (float*)alloc(DD * 4);
    float*     biasQ = (float*)alloc(DD * 4);
    _Float16*  ipWh  = (_Float16*)alloc(DD * CD * 2);
    _Float16*  ipWl  = (_Float16*)alloc(DD * CD * 2);
    _Float16*  kWh   = (_Float16*)alloc(DD * CD * 2);
    _Float16*  kWl   = (_Float16*)alloc(DD * CD * 2);
    _Float16*  qWh   = (_Float16*)alloc(DD * CD * 2);
    _Float16*  qWl   = (_Float16*)alloc(DD * CD * 2);
    _Float16*  dbWh  = (_Float16*)alloc(48 * 384 * 2);
    _Float16*  dbWl  = (_Float16*)alloc(48 * 384 * 2);
    _Float16*  gWh   = (_Float16*)alloc(DD * 384 * 2);
    _Float16*  gWl   = (_Float16*)alloc(DD * 384 * 2);
    _Float16*  oWh   = (_Float16*)alloc(96 * DD * 2);
    _Float16*  oWl   = (_Float16*)alloc(96 * DD * 2);
    float*     sd_ws = (float*)alloc((size_t)BZ * NG * DD * 4);
    float*     S_ws  = (float*)alloc((size_t)BZ * NG * DD * NS * 4);
    float*     H_ws  = (float*)alloc((size_t)BZ * NG * DD * NS * 4);
    float*     Sg    = (float*)alloc((size_t)BZ * NGRP * DD * NS * 4);
    float*     sdg   = (float*)alloc((size_t)BZ * NGRP * DD * 4);
    float*     Hgrp  = (float*)alloc((size_t)BZ * NGRP * DD * NS * 4);
    _Float16* yH = KpH;
    _Float16* yL = KpL;

    prep_kernel<<<dim3(DD, 2), 96, 0, stream>>>(k_ln_g, k_ln_b, k_w, k_b,
        q_ln_g, q_ln_b, q_w, q_b, gwK, wsumK, biasK, gwQ, wsumQ, biasQ);
    {
        const int total = 18432 * 5 + 73728;
        split_all_kernel<<<(total + 255) / 256, 256, 0, stream>>>(
            in_projw, gwK, gwQ, dtbc_w, gate_w, out_w,
            ipWh, ipWl, kWh, kWl, qWh, qWl, dbWh, dbWl, gWh, gWl, oWh, oWl);
    }

    mfma_projCH3<<<dim3(LL / 64, BZ, 3), 256, 0, stream>>>(
        x, K, Q, ipWh, ipWl, kWh, kWl, qWh, qWl,
        wsumK, biasK, wsumQ, biasQ, xin, KpH, KpL, QpH, QpL);
    conv_kernel<<<(MTOK / 4) * (DD / 4) / 256, 256, 0, stream>>>(xin, conv_w, conv_b, uH, uL);
    gemm_zx<<<(MTOK / 64) * 2, 256, 0, stream>>>(
        uH, uL, QpH, QpL, KpH, KpL, gWh, gWl, dbWh, dbWl, gate_b,
        zsH, zsL, dtbB, Bb, Cb);
    scan_pass1<<<dim3(NG, DD / 64, BZ), 64, 0, stream>>>(
        uH, uL, dtbB, Bb, A_log, dt_w, dt_b, sd_ws, S_ws);
    combine_a<<<(BZ * NGRP * DD * NS) / 256, 256, 0, stream>>>(sd_ws, S_ws, A_log, Sg, sdg);
    combine_b<<<(BZ * DD * NS) / 256, 256, 0, stream>>>(Sg, sdg, A_log, Hgrp);
    combine_c<<<(BZ * NGRP * DD * NS) / 256, 256, 0, stream>>>(sd_ws, S_ws, Hgrp, A_log, H_ws);
    scan_pass2<<<dim3(NG, DD / 64, BZ), 64, 0, stream>>>(
        uH, uL, dtbB, Bb, Cb, A_log, dt_w, dt_b, H_ws, zsH, zsL, Dvec, yH, yL);
    gemm_out<<<MTOK / 64, 256, 0, stream>>>(yH, yL, oWh, oWl, out);
}